// Round 16
// baseline (395.753 us; speedup 1.0000x reference)
//
#include <hip/hip_runtime.h>
#include <hip/hip_bf16.h>

#define DIM 2048
#define NH 16
#define HD 128
#define QD 1024
#define TOT 3072
#define BB 2
#define SS 2048
#define NTOK (BB*SS)
#define EPS 1e-5f

typedef __attribute__((ext_vector_type(4))) float f32x4;
typedef __attribute__((ext_vector_type(8))) short short8;
typedef __attribute__((ext_vector_type(8))) unsigned short u16x8;
typedef __attribute__((ext_vector_type(4))) unsigned short u16x4;
typedef __attribute__((ext_vector_type(4))) unsigned int u32x4;

__device__ __forceinline__ float b2f(unsigned short u){
    unsigned int x = ((unsigned int)u) << 16;
    return __builtin_bit_cast(float, x);
}
__device__ __forceinline__ unsigned short f2b(float f){
    unsigned int x = __builtin_bit_cast(unsigned int, f);
    x = (x + 0x7fffu + ((x >> 16) & 1u)) >> 16;
    return (unsigned short)x;
}
__device__ __forceinline__ float exp2_fast(float x){
    float r;
    asm("v_exp_f32 %0, %1" : "=v"(r) : "v"(x));
    return r;
}
__device__ __forceinline__ void store_c(float* p, float v){ *p = v; }
__device__ __forceinline__ void store_c(unsigned short* p, float v){ *p = f2b(v); }

#define MFMA16(a,b,c) __builtin_amdgcn_mfma_f32_16x16x32_bf16((a),(b),(c),0,0,0)

#define GLOAD16(g, l) __builtin_amdgcn_global_load_lds( \
    (const __attribute__((address_space(1))) unsigned int*)(g), \
    (__attribute__((address_space(3))) unsigned int*)(l), 16, 0, 0)

// ---------------- K0: weight-only f32 -> bf16 converts (activations fused into GEMM) -------
__device__ __forceinline__ void cvt8(const float* __restrict__ s,
                                     unsigned short* __restrict__ d, int i){
    const float4* p = reinterpret_cast<const float4*>(s + (size_t)i * 8);
    float4 a = p[0], b = p[1];
    u16x8 o;
    o[0]=f2b(a.x); o[1]=f2b(a.y); o[2]=f2b(a.z); o[3]=f2b(a.w);
    o[4]=f2b(b.x); o[5]=f2b(b.y); o[6]=f2b(b.z); o[7]=f2b(b.w);
    *reinterpret_cast<u16x8*>(d + (size_t)i * 8) = o;
}

__global__ __launch_bounds__(256) void cvt_w4(
    const float* __restrict__ s0, const float* __restrict__ s1,
    const float* __restrict__ s2, const float* __restrict__ s3,
    unsigned short* __restrict__ d0, unsigned short* __restrict__ d1,
    unsigned short* __restrict__ d2, unsigned short* __restrict__ d3)
{
    const int N0 = TOT*DIM/8;             // W_lc
    const int N1 = N0 + TOT*DIM/8;        // W_gc
    const int N2 = N1 + DIM*DIM/8;        // W_lo
    const int N3 = N2 + DIM*DIM/8;        // W_go
    for (int i = blockIdx.x * blockDim.x + threadIdx.x; i < N3;
         i += gridDim.x * blockDim.x){
        if      (i < N0) cvt8(s0, d0, i);
        else if (i < N1) cvt8(s1, d1, i - N0);
        else if (i < N2) cvt8(s2, d2, i - N1);
        else             cvt8(s3, d3, i - N2);
    }
}

// ---------------- K1a: 128x128 NT GEMM, A = f32 (fused convert), B = bf16 DMA --------------
// A-tiles reg-staged: coalesced f32 loads -> v_cvt_pk_bf16_f32 -> ds_write_b128 into the
// SAME XOR-swizzled layout (reg-staging can scatter). B stays on the proven gload_lds path.
// z-slice from HW dispatch id: XCDs 0-3 slice0, 4-7 slice1.
__global__ __launch_bounds__(256) void gemm_qkv(const float* __restrict__ A0,
                                                const unsigned short* __restrict__ B0,
                                                unsigned short* __restrict__ C0,
                                                const float* __restrict__ A1,
                                                const unsigned short* __restrict__ B1,
                                                unsigned short* __restrict__ C1,
                                                int M, int N, int K){
    __shared__ __attribute__((aligned(16))) unsigned short As[2][128*64];
    __shared__ __attribute__((aligned(16))) unsigned short Bs[2][128*64];
    const int t = threadIdx.x;
    const int lane = t & 63;
    const int w = t >> 6;
    const int wr = w >> 1, wc = w & 1;
    const int gx = gridDim.x;
    const int nwg = gx * gridDim.y;
    int zsel, swz;
    {
        const int glin = (int)(blockIdx.z * nwg + blockIdx.y * gx + blockIdx.x);
        const int xcd = glin & 7;
        const int i = glin >> 3;
        zsel = xcd >> 2;
        swz = (xcd & 3) * (nwg >> 2) + i;
    }
    const float* A = zsel ? A1 : A0;
    const unsigned short* B = zsel ? B1 : B0;
    unsigned short* C = zsel ? C1 : C0;
    const int m0 = (swz / gx) * 128, n0 = (swz % gx) * 128;
    const int l16 = lane & 15, lq = lane >> 4;

    f32x4 acc[4][4];
    const f32x4 z = {0.f, 0.f, 0.f, 0.f};
    #pragma unroll
    for (int m = 0; m < 4; ++m)
        #pragma unroll
        for (int n = 0; n < 4; ++n) acc[m][n] = z;

    // A: load f32 (8 elems = 2 float4), convert, write 16B to swizzled chunk index c
    auto stageA = [&](int kt, int bi){
        #pragma unroll
        for (int i = 0; i < 4; ++i){
            int c = t + 256 * i;
            int row = c >> 3, c8 = c & 7;
            int cg = (c8 ^ (row & 7)) * 8;
            const float4* src = reinterpret_cast<const float4*>(
                &A[(size_t)(m0 + row) * K + kt + cg]);
            float4 a = src[0], b = src[1];
            unsigned q0, q1, q2, q3;
            asm("v_cvt_pk_bf16_f32 %0, %1, %2" : "=v"(q0) : "v"(a.x), "v"(a.y));
            asm("v_cvt_pk_bf16_f32 %0, %1, %2" : "=v"(q1) : "v"(a.z), "v"(a.w));
            asm("v_cvt_pk_bf16_f32 %0, %1, %2" : "=v"(q2) : "v"(b.x), "v"(b.y));
            asm("v_cvt_pk_bf16_f32 %0, %1, %2" : "=v"(q3) : "v"(b.z), "v"(b.w));
            u32x4 o; o[0]=q0; o[1]=q1; o[2]=q2; o[3]=q3;
            *reinterpret_cast<u32x4*>((char*)&As[bi][0] + (size_t)c * 16) = o;
        }
    };
    auto stageB = [&](int kt, int bi){
        #pragma unroll
        for (int i = 0; i < 4; ++i){
            int c = t + 256 * i;
            int row = c >> 3, c8 = c & 7;
            int cg = (c8 ^ (row & 7)) * 8;
            GLOAD16(&B[(size_t)(n0 + row) * K + kt + cg],
                    (char*)&Bs[bi][0] + (size_t)(i * 256 + w * 64) * 16);
        }
    };

    stageA(0, 0); stageB(0, 0);
    __syncthreads();                 // drains vmcnt + lgkmcnt
    int cur = 0;

    for (int kt = 0; kt < K; kt += 64){
        if (kt + 64 < K){ stageB(kt + 64, cur ^ 1); stageA(kt + 64, cur ^ 1); }
        #pragma unroll
        for (int kk = 0; kk < 2; ++kk){
            short8 af[4], bf[4];
            #pragma unroll
            for (int m = 0; m < 4; ++m){
                int row = wr*64 + m*16 + l16;
                af[m] = *reinterpret_cast<const short8*>(
                    &As[cur][row*64 + (((kk*4 + lq) ^ (row & 7)) * 8)]);
            }
            #pragma unroll
            for (int n = 0; n < 4; ++n){
                int row = wc*64 + n*16 + l16;
                bf[n] = *reinterpret_cast<const short8*>(
                    &Bs[cur][row*64 + (((kk*4 + lq) ^ (row & 7)) * 8)]);
            }
            #pragma unroll
            for (int m = 0; m < 4; ++m)
                #pragma unroll
                for (int n = 0; n < 4; ++n)
                    acc[m][n] = MFMA16(af[m], bf[n], acc[m][n]);
        }
        __syncthreads();
        cur ^= 1;
    }
    #pragma unroll
    for (int m = 0; m < 4; ++m){
        int grow = m0 + wr*64 + m*16 + lq*4;
        #pragma unroll
        for (int n = 0; n < 4; ++n){
            int gcol = n0 + wc*64 + n*16 + l16;
            #pragma unroll
            for (int r = 0; r < 4; ++r)
                C[(size_t)(grow + r) * N + gcol] = f2b(acc[m][n][r]);
        }
    }
}

// ---------------- K1b: 256x256 8-phase GEMM — used for proj (256 blocks = 1/CU) ------------
__global__ __launch_bounds__(512, 2) void gemm256(
    const unsigned short* __restrict__ A0, const unsigned short* __restrict__ B0,
    unsigned short* __restrict__ C0,
    const unsigned short* __restrict__ A1, const unsigned short* __restrict__ B1,
    unsigned short* __restrict__ C1, int M, int N, int K)
{
    __shared__ __attribute__((aligned(16))) unsigned short LA[2][2][128*64];
    __shared__ __attribute__((aligned(16))) unsigned short LB[2][2][128*64];
    const int t = threadIdx.x;
    const int lane = t & 63, w = t >> 6;
    const int wr = w >> 2, wc = w & 3;
    const int l16 = lane & 15, lq = lane >> 4;
    const int gx = gridDim.x;
    const int nwg = gx * gridDim.y;
    int zsel, swz;
    if (gridDim.z == 2){
        const int glin = (int)(blockIdx.z * nwg + blockIdx.y * gx + blockIdx.x);
        const int xcd = glin & 7;
        const int i = glin >> 3;
        zsel = xcd >> 2;
        swz = (xcd & 3) * (nwg >> 2) + i;
    } else {
        const int lin = (int)(blockIdx.y * gx + blockIdx.x);
        swz = (lin & 7) * (nwg >> 3) + (lin >> 3);
        zsel = 0;
    }
    const unsigned short* A = zsel ? A1 : A0;
    const unsigned short* B = zsel ? B1 : B0;
    unsigned short* C = zsel ? C1 : C0;
    const int m0 = (swz / gx) * 256, n0 = (swz % gx) * 256;

    f32x4 acc[8][4];
    const f32x4 z = {0.f, 0.f, 0.f, 0.f};
    #pragma unroll
    for (int a = 0; a < 8; ++a)
        #pragma unroll
        for (int n = 0; n < 4; ++n) acc[a][n] = z;

    auto part = [&](const unsigned short* S, int rowbase, int kt, int j2, unsigned short* slab){
        int row = j2*64 + (t >> 3);
        int ch  = t & 7;
        GLOAD16(&S[(size_t)(rowbase + row) * K + kt*64 + ((ch ^ (row & 7)) * 8)],
                (char*)slab + (size_t)(j2*512 + w*64) * 16);
    };

    const int NT = K >> 6;
    part(B, n0+0,   0, 0, &LB[0][0][0]); part(B, n0+0,   0, 1, &LB[0][0][0]);
    part(B, n0+128, 0, 0, &LB[0][1][0]); part(B, n0+128, 0, 1, &LB[0][1][0]);
    part(A, m0+0,   0, 0, &LA[0][0][0]); part(A, m0+128, 0, 0, &LA[0][1][0]);
    part(A, m0+0,   0, 1, &LA[0][0][0]); part(A, m0+128, 0, 1, &LA[0][1][0]);
    if (NT > 1){
        part(B, n0+0,   1, 0, &LB[1][0][0]); part(B, n0+0,   1, 1, &LB[1][0][0]);
        part(A, m0+0,   1, 0, &LA[1][0][0]); part(A, m0+128, 1, 0, &LA[1][1][0]);
        part(B, n0+128, 1, 0, &LB[1][1][0]); part(B, n0+128, 1, 1, &LB[1][1][0]);
        asm volatile("s_waitcnt vmcnt(6)" ::: "memory");
    } else {
        asm volatile("s_waitcnt vmcnt(0)" ::: "memory");
    }
    __builtin_amdgcn_s_barrier();
    asm volatile("" ::: "memory");
    __builtin_amdgcn_sched_barrier(0);

    for (int kt = 0; kt < NT; ++kt){
        const int pc = kt & 1;
        const int p1 = pc ^ 1;
        short8 bfr[4][2];
        #pragma unroll
        for (int q = 0; q < 4; ++q){
            if (q == 0 && kt + 1 < NT){
                part(A, m0+0,   kt+1, 1, &LA[p1][0][0]);
                part(A, m0+128, kt+1, 1, &LA[p1][1][0]);
            }
            if (q == 1 && kt + 2 < NT){
                part(B, n0+0,   kt+2, 0, &LB[pc][0][0]);
                part(B, n0+0,   kt+2, 1, &LB[pc][0][0]);
            }
            if (q == 2 && kt + 2 < NT){
                part(A, m0+0,   kt+2, 0, &LA[pc][0][0]);
                part(A, m0+128, kt+2, 0, &LA[pc][1][0]);
            }
            if (q == 3 && kt + 2 < NT){
                part(B, n0+128, kt+2, 0, &LB[pc][1][0]);
                part(B, n0+128, kt+2, 1, &LB[pc][1][0]);
            }
            short8 afr[2][2];
            #pragma unroll
            for (int mi = 0; mi < 2; ++mi){
                int lr = q*32 + mi*16 + l16;
                #pragma unroll
                for (int kk = 0; kk < 2; ++kk)
                    afr[mi][kk] = *reinterpret_cast<const short8*>(
                        &LA[pc][wr][lr*64 + (((kk*4 + lq) ^ (lr & 7)) * 8)]);
            }
            if (q == 0){
                #pragma unroll
                for (int n = 0; n < 4; ++n){
                    int lb = (wc & 1)*64 + n*16 + l16;
                    #pragma unroll
                    for (int kk = 0; kk < 2; ++kk)
                        bfr[n][kk] = *reinterpret_cast<const short8*>(
                            &LB[pc][wc >> 1][lb*64 + (((kk*4 + lq) ^ (lb & 7)) * 8)]);
                }
            }
            __builtin_amdgcn_s_setprio(1);
            #pragma unroll
            for (int kk = 0; kk < 2; ++kk)
                #pragma unroll
                for (int mi = 0; mi < 2; ++mi)
                    #pragma unroll
                    for (int n = 0; n < 4; ++n)
                        acc[q*2 + mi][n] = MFMA16(afr[mi][kk], bfr[n][kk], acc[q*2 + mi][n]);
            __builtin_amdgcn_s_setprio(0);
            if (q == 3 && kt + 1 < NT){
                if (kt + 2 < NT) asm volatile("s_waitcnt vmcnt(6)" ::: "memory");
                else             asm volatile("s_waitcnt vmcnt(0)" ::: "memory");
            }
            __builtin_amdgcn_s_barrier();
            asm volatile("" ::: "memory");
            __builtin_amdgcn_sched_barrier(0);
        }
    }

    #pragma unroll
    for (int a = 0; a < 8; ++a){
        int grow = m0 + wr*128 + (a >> 1)*32 + (a & 1)*16 + lq*4;
        #pragma unroll
        for (int n = 0; n < 4; ++n){
            int gcol = n0 + wc*64 + n*16 + l16;
            #pragma unroll
            for (int r = 0; r < 4; ++r)
                C[(size_t)(grow + r) * N + gcol] = f2b(acc[a][n][r]);
        }
    }
}

// ---------------- K2: qkv postprocess (rmsnorm + rope + concat + cat-rmsnorm) ----------------
__global__ __launch_bounds__(256) void qkv_post(
    const unsigned short* __restrict__ comb_lc, const unsigned short* __restrict__ comb_gc,
    const float* __restrict__ freqs,
    const float* __restrict__ q_lc_nw, const float* __restrict__ k_lc_nw,
    const float* __restrict__ q_gc_nw, const float* __restrict__ k_gc_nw,
    const float* __restrict__ q_cat_nw, const float* __restrict__ k_cat_nw,
    unsigned short* __restrict__ xq, unsigned short* __restrict__ xk,
    unsigned short* __restrict__ xv)
{
    __shared__ float qcat[16][128];
    __shared__ float kcat[16][128];
    __shared__ float rbuf[4][4];
    const int tok = blockIdx.x;
    const int s = tok & (SS - 1);
    const unsigned short* clc = comb_lc + (size_t)tok * TOT;
    const unsigned short* cgc = comb_gc + (size_t)tok * TOT;
    const int t = threadIdx.x;
    const int lane = t & 63, w = t >> 6;

    const unsigned short* segs[4] = { clc, clc + QD, cgc, cgc + QD };
    const float* wts[4] = { q_lc_nw, k_lc_nw, q_gc_nw, k_gc_nw };

    float ss4[4];
    #pragma unroll
    for (int sg = 0; sg < 4; ++sg){
        u16x4 v = *reinterpret_cast<const u16x4*>(segs[sg] + t * 4);
        float acc = 0.f;
        #pragma unroll
        for (int j = 0; j < 4; ++j){ float f = b2f(v[j]); acc += f * f; }
        ss4[sg] = acc;
    }
    #pragma unroll
    for (int sg = 0; sg < 4; ++sg){
        float v = ss4[sg];
        #pragma unroll
        for (int o = 32; o >= 1; o >>= 1) v += __shfl_xor(v, o);
        if (lane == 0) rbuf[sg][w] = v;
    }
    __syncthreads();
    float rms[4];
    #pragma unroll
    for (int sg = 0; sg < 4; ++sg){
        float tot = rbuf[sg][0] + rbuf[sg][1] + rbuf[sg][2] + rbuf[sg][3];
        rms[sg] = rsqrtf(tot * (1.f / QD) + EPS);
    }

    #pragma unroll
    for (int sg = 0; sg < 4; ++sg){
        const unsigned short* seg = segs[sg];
        const float* wt = wts[sg];
        const float rf = rms[sg];
        float (*dst)[128] = (sg == 0 || sg == 2) ? qcat : kcat;
        const int coff = (sg >= 2) ? 64 : 0;
        #pragma unroll
        for (int pi = 0; pi < 2; ++pi){
            int p = t + pi * 256;
            int h = p >> 5, j = p & 31;
            int idx = h * 64 + 2 * j;
            float xr = b2f(seg[idx])     * rf * wt[idx];
            float xi = b2f(seg[idx + 1]) * rf * wt[idx + 1];
            float fr = freqs[(size_t)s * 32 + j];
            float cs = __cosf(fr), sn = __sinf(fr);
            dst[h][coff + 2*j]     = xr * cs - xi * sn;
            dst[h][coff + 2*j + 1] = xr * sn + xi * cs;
        }
    }

    {
        int i0 = t * 4;
        int h = i0 >> 6, d = i0 & 63;
        u16x4 vlc = *reinterpret_cast<const u16x4*>(clc + 2048 + i0);
        u16x4 vgc = *reinterpret_cast<const u16x4*>(cgc + 2048 + i0);
        *reinterpret_cast<u16x4*>(&xv[(size_t)tok * DIM + h * 128 + d])      = vlc;
        *reinterpret_cast<u16x4*>(&xv[(size_t)tok * DIM + h * 128 + 64 + d]) = vgc;
    }
    __syncthreads();

    {
        int h = t >> 4, sub = t & 15;
        float sq = 0.f, sk = 0.f;
        #pragma unroll
        for (int j = 0; j < 8; ++j){
            float a = qcat[h][sub*8 + j]; sq += a * a;
            float b = kcat[h][sub*8 + j]; sk += b * b;
        }
        #pragma unroll
        for (int o = 1; o < 16; o <<= 1){ sq += __shfl_xor(sq, o); sk += __shfl_xor(sk, o); }
        float rq = rsqrtf(sq * (1.f / 128) + EPS);
        float rk = rsqrtf(sk * (1.f / 128) + EPS);
        u16x8 oq, ok;
        #pragma unroll
        for (int j = 0; j < 8; ++j){
            int d = sub*8 + j;
            oq[j] = f2b(qcat[h][d] * rq * q_cat_nw[d]);
            ok[j] = f2b(kcat[h][d] * rk * k_cat_nw[d]);
        }
        *reinterpret_cast<u16x8*>(&xq[(size_t)tok * DIM + h * 128 + sub*8]) = oq;
        *reinterpret_cast<u16x8*>(&xk[(size_t)tok * DIM + h * 128 + sub*8]) = ok;
    }
}

// ---------------- K4: V transpose -> xvT[b,h,d,s] ----------------
__global__ __launch_bounds__(256) void transpose_v(const unsigned short* __restrict__ xv,
                                                   unsigned short* __restrict__ xvT){
    __shared__ unsigned short tile[128][129];
    const int blk = blockIdx.x;
    const int st = blk & 15;
    const int bh = blk >> 4;
    const int b = bh >> 4, h = bh & 15;
    const int t = threadIdx.x;
    const int s0 = st * 128;
    #pragma unroll
    for (int i = 0; i < 8; ++i){
        int c = t + 256 * i;
        int r = c >> 4, dc = c & 15;
        u16x8 v = *reinterpret_cast<const u16x8*>(&xv[((size_t)(b*SS + s0 + r)) * DIM + h*HD + dc*8]);
        #pragma unroll
        for (int j = 0; j < 8; ++j) tile[r][dc*8 + j] = v[j];
    }
    __syncthreads();
    #pragma unroll
    for (int i = 0; i < 8; ++i){
        int c = t + 256 * i;
        int d = c >> 4, sc = c & 15;
        u16x8 o;
        #pragma unroll
        for (int j = 0; j < 8; ++j) o[j] = tile[sc*8 + j][d];
        *reinterpret_cast<u16x8*>(&xvT[((size_t)bh * HD + d) * SS + s0 + sc*8]) = o;
    }
}

// ---------------- K3: flash attention — QBLK=128, static-bias softmax (proven) -------------
__global__ __launch_bounds__(256) void attn_fwd(const unsigned short* __restrict__ xq,
                                                const unsigned short* __restrict__ xk,
                                                const unsigned short* __restrict__ xvT,
                                                unsigned short* __restrict__ attn_out){
    __shared__ __attribute__((aligned(16))) unsigned short Kl[2][64 * 128];
    __shared__ __attribute__((aligned(16))) unsigned short Vt[2][128 * 64];
    __shared__ __attribute__((aligned(16))) unsigned short Pl[4][2][16 * 64];
    const int blk = ((int)blockIdx.x & 7) * 64 + ((int)blockIdx.x >> 3);
    const int qt = blk & 15, h = (blk >> 4) & 15, b = blk >> 8;
    const int t = threadIdx.x, lane = t & 63, w = t >> 6;
    const int l16 = lane & 15, lq = lane >> 4;
    const float scale2 = 0.12751744751f;
    const float MBIAS = 16.6f;
    const int qbase = qt * 128 + w * 32;

    short8 qf[2][4];
    #pragma unroll
    for (int g = 0; g < 2; ++g)
        #pragma unroll
        for (int ks = 0; ks < 4; ++ks)
            qf[g][ks] = *reinterpret_cast<const short8*>(
                &xq[((size_t)(b*SS + qbase + g*16 + l16)) * DIM + h*HD + ks*32 + lq*8]);

    float psum[2] = {0.f, 0.f};
    f32x4 O[2][8];
    const f32x4 z = {0.f, 0.f, 0.f, 0.f};
    #pragma unroll
    for (int g = 0; g < 2; ++g)
        #pragma unroll
        for (int dn = 0; dn < 8; ++dn) O[g][dn] = z;

    const size_t kbase = (size_t)(b*SS) * DIM + h*HD;
    const size_t vbase = ((size_t)(b*NH + h)) * HD * SS;

    auto stage = [&](int kt, int bi){
        #pragma unroll
        for (int i = 0; i < 4; ++i){
            int slot = i*256 + w*64 + lane;
            int r = slot >> 4, dc = slot & 15;
            GLOAD16(&xk[kbase + (size_t)(kt*64 + r) * DIM + ((dc ^ (r & 7)) * 8)],
                    (char*)&Kl[bi][0] + (size_t)(i*256 + w*64) * 16);
            int d = slot >> 3, kc = slot & 7;
            GLOAD16(&xvT[vbase + (size_t)d * SS + kt*64 + ((kc ^ (d & 7)) * 8)],
                    (char*)&Vt[bi][0] + (size_t)(i*256 + w*64) * 16);
        }
    };

    stage(0, 0);
    __syncthreads();

    int cur = 0;

    for (int kt = 0; kt < SS/64; ++kt){
        if (kt + 1 < SS/64) stage(kt + 1, cur ^ 1);

        const unsigned short* Kc = Kl[cur];
        const unsigned short* Vc = Vt[cur];

        #pragma unroll
        for (int g = 0; g < 2; ++g){
            f32x4 St[4];
            #pragma unroll
            for (int kn = 0; kn < 4; ++kn) St[kn] = z;
            __builtin_amdgcn_s_setprio(1);
            #pragma unroll
            for (int kn = 0; kn < 4; ++kn){
                int kr = kn*16 + l16;
                #pragma unroll
                for (int ks = 0; ks < 4; ++ks){
                    short8 ak = *reinterpret_cast<const short8*>(
                        &Kc[kr*128 + (((ks*4 + lq) ^ (kr & 7)) * 8)]);
                    St[kn] = MFMA16(ak, qf[g][ks], St[kn]);
                }
            }
            __builtin_amdgcn_s_setprio(0);

            unsigned short* P = Pl[w][g];
            #pragma unroll
            for (int kn = 0; kn < 4; ++kn){
                float p0 = exp2_fast(St[kn][0]*scale2 - MBIAS);
                float p1 = exp2_fast(St[kn][1]*scale2 - MBIAS);
                float p2 = exp2_fast(St[kn][2]*scale2 - MBIAS);
                float p3 = exp2_fast(St[kn][3]*scale2 - MBIAS);
                psum[g] += (p0 + p1) + (p2 + p3);
                unsigned lo, hi;
                asm("v_cvt_pk_bf16_f32 %0, %1, %2" : "=v"(lo) : "v"(p0), "v"(p1));
                asm("v_cvt_pk_bf16_f32 %0, %1, %2" : "=v"(hi) : "v"(p2), "v"(p3));
                uint2 pk2; pk2.x = lo; pk2.y = hi;
                int kk = kn >> 1;
                int lqp = (kn & 1)*2 + (lq >> 1);
                *reinterpret_cast<uint2*>(&P[(kk*64 + lqp*16 + l16)*8 + (lq & 1)*4]) = pk2;
            }
        }
        asm volatile("s_waitcnt lgkmcnt(0)" ::: "memory");
        __builtin_amdgcn_sched_barrier(0);

        __builtin_amdgcn_s_setprio(1);
        #pragma unroll
        for (int kk = 0; kk < 2; ++kk){
            short8 pb0 = *reinterpret_cast<const short8*>(&Pl[w][0][(kk*64 + lq*16 + l16)*8]);
            short8 pb1 = *reinterpret_cast<const short8*>(&Pl[w][1][(kk*64 + lq*16 + l16)*8]);
            #pragma unroll
            for (int dn = 0; dn < 8; ++dn){
                int dr = dn*16 + l16;
                short8 av = *reinterpret_cast<const short8*>(
                    &Vc[dr*64 + (((kk*4 + lq) ^ (dr & 7)) * 8)]);
                O[0][dn] = MFMA16(av, pb0, O[0][dn]);
                O[1][dn] = MFMA16(av, pb1, O[1][dn]);
            }
        }
        __builtin_amdgcn_s_setprio(0);

        __syncthreads();
        cur ^= 1;
    }

    #pragma unroll
    for (int g = 0; g < 2; ++g){
        float ps = psum[g];
        ps += __shfl_xor(ps, 16);
        ps += __shfl_xor(ps, 32);
        float inv = 1.f / ps;
        #pragma unroll
        for (int dn = 0; dn < 8; ++dn){
            u16x4 o4;
            #pragma unroll
            for (int r = 0; r < 4; ++r) o4[r] = f2b(O[g][dn][r] * inv);
            *reinterpret_cast<u16x4*>(
                &attn_out[((size_t)(b*SS + qbase + g*16 + l16)) * DIM + h*HD + dn*16 + lq*4]) = o4;
        }
    }
}

// ---------------- K5: bias + rmsnorm epilogue, merged proj [NTOK][2*DIM] ----------------
__global__ __launch_bounds__(256) void proj_norm2(const unsigned short* __restrict__ proj,
                                                  const float* __restrict__ b_lo,
                                                  const float* __restrict__ b_go,
                                                  const float* __restrict__ w_lc,
                                                  const float* __restrict__ w_gc,
                                                  float* __restrict__ out){
    __shared__ float buf[DIM];
    __shared__ float rbuf[4];
    const int half = blockIdx.x >> 12;
    const int row  = blockIdx.x & (NTOK - 1);
    const unsigned short* p = proj + (size_t)row * (2*DIM) + (size_t)half * DIM;
    const float* bias = half ? b_go : b_lo;
    const float* w    = half ? w_gc : w_lc;
    float* o = out + (size_t)half * NTOK * DIM + (size_t)row * DIM;
    const int t = threadIdx.x;
    const int lane = t & 63, wv = t >> 6;
    float ssq = 0.f;
    #pragma unroll
    for (int i = 0; i < 8; ++i){
        int c = t + i * 256;
        float v = b2f(p[c]) + bias[c];
        buf[c] = v;
        ssq += v * v;
    }
    #pragma unroll
    for (int o2 = 32; o2 >= 1; o2 >>= 1) ssq += __shfl_xor(ssq, o2);
    if (lane == 0) rbuf[wv] = ssq;
    __syncthreads();
    float tot = rbuf[0] + rbuf[1] + rbuf[2] + rbuf[3];
    float rr = rsqrtf(tot * (1.f / DIM) + EPS);
    #pragma unroll
    for (int i = 0; i < 8; ++i){
        int c = t + i * 256;
        o[c] = buf[c] * rr * w[c];
    }
}

extern "C" void kernel_launch(void* const* d_in, const int* in_sizes, int n_in,
                              void* d_out, int out_size, void* d_ws, size_t ws_size,
                              hipStream_t stream)
{
    const float* local_c  = (const float*)d_in[0];
    const float* global_c = (const float*)d_in[1];
    const float* freqs    = (const float*)d_in[2];
    const float* W_lc     = (const float*)d_in[3];
    const float* W_gc     = (const float*)d_in[4];
    const float* q_lc_nw  = (const float*)d_in[5];
    const float* k_lc_nw  = (const float*)d_in[6];
    const float* q_gc_nw  = (const float*)d_in[7];
    const float* k_gc_nw  = (const float*)d_in[8];
    const float* q_cat_nw = (const float*)d_in[9];
    const float* k_cat_nw = (const float*)d_in[10];
    const float* W_lo     = (const float*)d_in[11];
    const float* b_lo     = (const float*)d_in[12];
    const float* lc_on_w  = (const float*)d_in[13];
    const float* W_go     = (const float*)d_in[14];
    const float* b_go     = (const float*)d_in[15];
    const float* gc_on_w  = (const float*)d_in[16];
    float* out = (float*)d_out;

    // ---- aliased workspace arena ----
    char* ws = (char*)d_ws;
    const size_t SZ_WLO  = (size_t)DIM * DIM * 2;
    const size_t SZ_WLC  = (size_t)TOT * DIM * 2;
    const size_t SZ_TOK2 = (size_t)NTOK * DIM * 2;
    const size_t SZ_COMB = (size_t)NTOK * TOT * 2;

    unsigned short* Wlo_b  = (unsigned short*)(ws);               // Wlo+Wgo contiguous => merged B
    unsigned short* Wgo_b  = (unsigned short*)(ws + SZ_WLO);
    char*           slotW  = ws + 2*SZ_WLO;
    unsigned short* Wlc_b  = (unsigned short*)(slotW);
    unsigned short* Wgc_b  = (unsigned short*)(slotW + SZ_WLC);
    unsigned short* xv     = (unsigned short*)(slotW);            // alias: Wlc/Wgc dead after QKV GEMM
    char*           slotE  = ws + 2*SZ_WLO + 2*SZ_WLC;
    char*           slotF  = slotE + SZ_TOK2;
    unsigned short* xq     = (unsigned short*)slotE;
    unsigned short* xk     = (unsigned short*)slotF;
    unsigned short* proj   = (unsigned short*)slotE;              // merged [NTOK][2*DIM]
    char*           slotG  = slotF + SZ_TOK2;
    char*           slotH  = slotG + SZ_COMB;
    unsigned short* comb_lc= (unsigned short*)slotG;
    unsigned short* comb_gc= (unsigned short*)slotH;
    unsigned short* xvT    = (unsigned short*)slotG;
    unsigned short* attn_o = (unsigned short*)slotH;
    (void)ws_size;

    // 1) weight converts only (activation convert fused into QKV GEMM)
    cvt_w4<<<2048, 256, 0, stream>>>(W_lc, W_gc, W_lo, W_go,
                                     Wlc_b, Wgc_b, Wlo_b, Wgo_b);

    // 2) both QKV GEMMs: 128^2 tile, f32-A fused convert, z-batched (1536 blocks)
    dim3 g1(TOT / 128, NTOK / 128, 2);
    gemm_qkv<<<g1, 256, 0, stream>>>(local_c, Wlc_b, comb_lc,
                                     global_c, Wgc_b, comb_gc, NTOK, TOT, DIM);

    // 3) norms + rope + concat
    qkv_post<<<NTOK, 256, 0, stream>>>(comb_lc, comb_gc, freqs,
                                       q_lc_nw, k_lc_nw, q_gc_nw, k_gc_nw,
                                       q_cat_nw, k_cat_nw, xq, xk, xv);

    // 4) V transpose
    transpose_v<<<512, 256, 0, stream>>>(xv, xvT);

    // 5) attention (QBLK=128)
    attn_fwd<<<512, 256, 0, stream>>>(xq, xk, xvT, attn_o);

    // 6) output projection: 256^2 8-phase (256 blocks = exactly 1/CU, no tail)
    dim3 g2(2 * DIM / 256, NTOK / 256, 1);
    gemm256<<<g2, 512, 0, stream>>>(attn_o, Wlo_b, proj,
                                    attn_o, Wlo_b, proj, NTOK, 2*DIM, DIM);

    // 7) final norms
    proj_norm2<<<2*NTOK, 256, 0, stream>>>(proj, b_lo, b_go, lc_on_w, gc_on_w, out);
}

// Round 17
// 395.088 us; speedup vs baseline: 1.0017x; 1.0017x over previous
//
#include <hip/hip_runtime.h>
#include <hip/hip_bf16.h>

#define DIM 2048
#define NH 16
#define HD 128
#define QD 1024
#define TOT 3072
#define BB 2
#define SS 2048
#define NTOK (BB*SS)
#define EPS 1e-5f

typedef __attribute__((ext_vector_type(4))) float f32x4;
typedef __attribute__((ext_vector_type(8))) short short8;
typedef __attribute__((ext_vector_type(8))) unsigned short u16x8;
typedef __attribute__((ext_vector_type(4))) unsigned short u16x4;
typedef __attribute__((ext_vector_type(4))) unsigned int u32x4;

__device__ __forceinline__ float b2f(unsigned short u){
    unsigned int x = ((unsigned int)u) << 16;
    return __builtin_bit_cast(float, x);
}
__device__ __forceinline__ unsigned short f2b(float f){
    unsigned int x = __builtin_bit_cast(unsigned int, f);
    x = (x + 0x7fffu + ((x >> 16) & 1u)) >> 16;
    return (unsigned short)x;
}
__device__ __forceinline__ float exp2_fast(float x){
    float r;
    asm("v_exp_f32 %0, %1" : "=v"(r) : "v"(x));
    return r;
}
__device__ __forceinline__ void store_c(float* p, float v){ *p = v; }
__device__ __forceinline__ void store_c(unsigned short* p, float v){ *p = f2b(v); }

#define MFMA16(a,b,c) __builtin_amdgcn_mfma_f32_16x16x32_bf16((a),(b),(c),0,0,0)

#define GLOAD16(g, l) __builtin_amdgcn_global_load_lds( \
    (const __attribute__((address_space(1))) unsigned int*)(g), \
    (__attribute__((address_space(3))) unsigned int*)(l), 16, 0, 0)

// ---------------- K0: weight-only f32 -> bf16 converts ----------------
__device__ __forceinline__ void cvt8(const float* __restrict__ s,
                                     unsigned short* __restrict__ d, int i){
    const float4* p = reinterpret_cast<const float4*>(s + (size_t)i * 8);
    float4 a = p[0], b = p[1];
    u16x8 o;
    o[0]=f2b(a.x); o[1]=f2b(a.y); o[2]=f2b(a.z); o[3]=f2b(a.w);
    o[4]=f2b(b.x); o[5]=f2b(b.y); o[6]=f2b(b.z); o[7]=f2b(b.w);
    *reinterpret_cast<u16x8*>(d + (size_t)i * 8) = o;
}

__global__ __launch_bounds__(256) void cvt_w4(
    const float* __restrict__ s0, const float* __restrict__ s1,
    const float* __restrict__ s2, const float* __restrict__ s3,
    unsigned short* __restrict__ d0, unsigned short* __restrict__ d1,
    unsigned short* __restrict__ d2, unsigned short* __restrict__ d3)
{
    const int N0 = TOT*DIM/8;
    const int N1 = N0 + TOT*DIM/8;
    const int N2 = N1 + DIM*DIM/8;
    const int N3 = N2 + DIM*DIM/8;
    for (int i = blockIdx.x * blockDim.x + threadIdx.x; i < N3;
         i += gridDim.x * blockDim.x){
        if      (i < N0) cvt8(s0, d0, i);
        else if (i < N1) cvt8(s1, d1, i - N0);
        else if (i < N2) cvt8(s2, d2, i - N1);
        else             cvt8(s3, d3, i - N2);
    }
}

// ---------------- K1a: 128x128 NT GEMM, A = f32 via T14 split (load-early / write-late) ----
// loadA(kt+1) issues f32 loads at iteration top (no wait); MFMA on cur runs with loads in
// flight; writeA(cur^1) converts + ds_writes AFTER the MFMA phase (vmcnt wait lands here).
// WAR on buf^1 protected by previous iteration's barrier. B stays on gload_lds DMA.
__global__ __launch_bounds__(256) void gemm_qkv(const float* __restrict__ A0,
                                                const unsigned short* __restrict__ B0,
                                                unsigned short* __restrict__ C0,
                                                const float* __restrict__ A1,
                                                const unsigned short* __restrict__ B1,
                                                unsigned short* __restrict__ C1,
                                                int M, int N, int K){
    __shared__ __attribute__((aligned(16))) unsigned short As[2][128*64];
    __shared__ __attribute__((aligned(16))) unsigned short Bs[2][128*64];
    const int t = threadIdx.x;
    const int lane = t & 63;
    const int w = t >> 6;
    const int wr = w >> 1, wc = w & 1;
    const int gx = gridDim.x;
    const int nwg = gx * gridDim.y;
    int zsel, swz;
    {
        const int glin = (int)(blockIdx.z * nwg + blockIdx.y * gx + blockIdx.x);
        const int xcd = glin & 7;
        const int i = glin >> 3;
        zsel = xcd >> 2;
        swz = (xcd & 3) * (nwg >> 2) + i;
    }
    const float* A = zsel ? A1 : A0;
    const unsigned short* B = zsel ? B1 : B0;
    unsigned short* C = zsel ? C1 : C0;
    const int m0 = (swz / gx) * 128, n0 = (swz % gx) * 128;
    const int l16 = lane & 15, lq = lane >> 4;

    f32x4 acc[4][4];
    const f32x4 z = {0.f, 0.f, 0.f, 0.f};
    #pragma unroll
    for (int m = 0; m < 4; ++m)
        #pragma unroll
        for (int n = 0; n < 4; ++n) acc[m][n] = z;

    float4 areg[4][2];   // in-flight A tile (f32), 32 VGPRs

    auto loadA = [&](int kt){
        #pragma unroll
        for (int i = 0; i < 4; ++i){
            int c = t + 256 * i;
            int row = c >> 3, c8 = c & 7;
            int cg = (c8 ^ (row & 7)) * 8;
            const float4* src = reinterpret_cast<const float4*>(
                &A[(size_t)(m0 + row) * K + kt + cg]);
            areg[i][0] = src[0];
            areg[i][1] = src[1];
        }
    };
    auto writeA = [&](int bi){
        #pragma unroll
        for (int i = 0; i < 4; ++i){
            int c = t + 256 * i;
            float4 a = areg[i][0], b = areg[i][1];
            unsigned q0, q1, q2, q3;
            asm("v_cvt_pk_bf16_f32 %0, %1, %2" : "=v"(q0) : "v"(a.x), "v"(a.y));
            asm("v_cvt_pk_bf16_f32 %0, %1, %2" : "=v"(q1) : "v"(a.z), "v"(a.w));
            asm("v_cvt_pk_bf16_f32 %0, %1, %2" : "=v"(q2) : "v"(b.x), "v"(b.y));
            asm("v_cvt_pk_bf16_f32 %0, %1, %2" : "=v"(q3) : "v"(b.z), "v"(b.w));
            u32x4 o; o[0]=q0; o[1]=q1; o[2]=q2; o[3]=q3;
            *reinterpret_cast<u32x4*>((char*)&As[bi][0] + (size_t)c * 16) = o;
        }
    };
    auto stageB = [&](int kt, int bi){
        #pragma unroll
        for (int i = 0; i < 4; ++i){
            int c = t + 256 * i;
            int row = c >> 3, c8 = c & 7;
            int cg = (c8 ^ (row & 7)) * 8;
            GLOAD16(&B[(size_t)(n0 + row) * K + kt + cg],
                    (char*)&Bs[bi][0] + (size_t)(i * 256 + w * 64) * 16);
        }
    };

    // prologue: tile 0
    loadA(0); stageB(0, 0);
    writeA(0);                       // waits A loads (vmcnt), B DMA still in flight
    __syncthreads();                 // drains everything; tile 0 resident
    int cur = 0;

    for (int kt = 0; kt < K; kt += 64){
        const bool more = (kt + 64 < K);
        if (more){ loadA(kt + 64); stageB(kt + 64, cur ^ 1); }  // issue only, no wait
        #pragma unroll
        for (int kk = 0; kk < 2; ++kk){
            short8 af[4], bf[4];
            #pragma unroll
            for (int m = 0; m < 4; ++m){
                int row = wr*64 + m*16 + l16;
                af[m] = *reinterpret_cast<const short8*>(
                    &As[cur][row*64 + (((kk*4 + lq) ^ (row & 7)) * 8)]);
            }
            #pragma unroll
            for (int n = 0; n < 4; ++n){
                int row = wc*64 + n*16 + l16;
                bf[n] = *reinterpret_cast<const short8*>(
                    &Bs[cur][row*64 + (((kk*4 + lq) ^ (row & 7)) * 8)]);
            }
            #pragma unroll
            for (int m = 0; m < 4; ++m)
                #pragma unroll
                for (int n = 0; n < 4; ++n)
                    acc[m][n] = MFMA16(af[m], bf[n], acc[m][n]);
        }
        if (more) writeA(cur ^ 1);   // cvt+ds_write after MFMA phase; loads had full overlap
        __syncthreads();
        cur ^= 1;
    }
    #pragma unroll
    for (int m = 0; m < 4; ++m){
        int grow = m0 + wr*64 + m*16 + lq*4;
        #pragma unroll
        for (int n = 0; n < 4; ++n){
            int gcol = n0 + wc*64 + n*16 + l16;
            #pragma unroll
            for (int r = 0; r < 4; ++r)
                C[(size_t)(grow + r) * N + gcol] = f2b(acc[m][n][r]);
        }
    }
}

// ---------------- K1b: 256x256 8-phase GEMM — used for proj (256 blocks = 1/CU) ------------
__global__ __launch_bounds__(512, 2) void gemm256(
    const unsigned short* __restrict__ A0, const unsigned short* __restrict__ B0,
    unsigned short* __restrict__ C0,
    const unsigned short* __restrict__ A1, const unsigned short* __restrict__ B1,
    unsigned short* __restrict__ C1, int M, int N, int K)
{
    __shared__ __attribute__((aligned(16))) unsigned short LA[2][2][128*64];
    __shared__ __attribute__((aligned(16))) unsigned short LB[2][2][128*64];
    const int t = threadIdx.x;
    const int lane = t & 63, w = t >> 6;
    const int wr = w >> 2, wc = w & 3;
    const int l16 = lane & 15, lq = lane >> 4;
    const int gx = gridDim.x;
    const int nwg = gx * gridDim.y;
    int zsel, swz;
    if (gridDim.z == 2){
        const int glin = (int)(blockIdx.z * nwg + blockIdx.y * gx + blockIdx.x);
        const int xcd = glin & 7;
        const int i = glin >> 3;
        zsel = xcd >> 2;
        swz = (xcd & 3) * (nwg >> 2) + i;
    } else {
        const int lin = (int)(blockIdx.y * gx + blockIdx.x);
        swz = (lin & 7) * (nwg >> 3) + (lin >> 3);
        zsel = 0;
    }
    const unsigned short* A = zsel ? A1 : A0;
    const unsigned short* B = zsel ? B1 : B0;
    unsigned short* C = zsel ? C1 : C0;
    const int m0 = (swz / gx) * 256, n0 = (swz % gx) * 256;

    f32x4 acc[8][4];
    const f32x4 z = {0.f, 0.f, 0.f, 0.f};
    #pragma unroll
    for (int a = 0; a < 8; ++a)
        #pragma unroll
        for (int n = 0; n < 4; ++n) acc[a][n] = z;

    auto part = [&](const unsigned short* S, int rowbase, int kt, int j2, unsigned short* slab){
        int row = j2*64 + (t >> 3);
        int ch  = t & 7;
        GLOAD16(&S[(size_t)(rowbase + row) * K + kt*64 + ((ch ^ (row & 7)) * 8)],
                (char*)slab + (size_t)(j2*512 + w*64) * 16);
    };

    const int NT = K >> 6;
    part(B, n0+0,   0, 0, &LB[0][0][0]); part(B, n0+0,   0, 1, &LB[0][0][0]);
    part(B, n0+128, 0, 0, &LB[0][1][0]); part(B, n0+128, 0, 1, &LB[0][1][0]);
    part(A, m0+0,   0, 0, &LA[0][0][0]); part(A, m0+128, 0, 0, &LA[0][1][0]);
    part(A, m0+0,   0, 1, &LA[0][0][0]); part(A, m0+128, 0, 1, &LA[0][1][0]);
    if (NT > 1){
        part(B, n0+0,   1, 0, &LB[1][0][0]); part(B, n0+0,   1, 1, &LB[1][0][0]);
        part(A, m0+0,   1, 0, &LA[1][0][0]); part(A, m0+128, 1, 0, &LA[1][1][0]);
        part(B, n0+128, 1, 0, &LB[1][1][0]); part(B, n0+128, 1, 1, &LB[1][1][0]);
        asm volatile("s_waitcnt vmcnt(6)" ::: "memory");
    } else {
        asm volatile("s_waitcnt vmcnt(0)" ::: "memory");
    }
    __builtin_amdgcn_s_barrier();
    asm volatile("" ::: "memory");
    __builtin_amdgcn_sched_barrier(0);

    for (int kt = 0; kt < NT; ++kt){
        const int pc = kt & 1;
        const int p1 = pc ^ 1;
        short8 bfr[4][2];
        #pragma unroll
        for (int q = 0; q < 4; ++q){
            if (q == 0 && kt + 1 < NT){
                part(A, m0+0,   kt+1, 1, &LA[p1][0][0]);
                part(A, m0+128, kt+1, 1, &LA[p1][1][0]);
            }
            if (q == 1 && kt + 2 < NT){
                part(B, n0+0,   kt+2, 0, &LB[pc][0][0]);
                part(B, n0+0,   kt+2, 1, &LB[pc][0][0]);
            }
            if (q == 2 && kt + 2 < NT){
                part(A, m0+0,   kt+2, 0, &LA[pc][0][0]);
                part(A, m0+128, kt+2, 0, &LA[pc][1][0]);
            }
            if (q == 3 && kt + 2 < NT){
                part(B, n0+128, kt+2, 0, &LB[pc][1][0]);
                part(B, n0+128, kt+2, 1, &LB[pc][1][0]);
            }
            short8 afr[2][2];
            #pragma unroll
            for (int mi = 0; mi < 2; ++mi){
                int lr = q*32 + mi*16 + l16;
                #pragma unroll
                for (int kk = 0; kk < 2; ++kk)
                    afr[mi][kk] = *reinterpret_cast<const short8*>(
                        &LA[pc][wr][lr*64 + (((kk*4 + lq) ^ (lr & 7)) * 8)]);
            }
            if (q == 0){
                #pragma unroll
                for (int n = 0; n < 4; ++n){
                    int lb = (wc & 1)*64 + n*16 + l16;
                    #pragma unroll
                    for (int kk = 0; kk < 2; ++kk)
                        bfr[n][kk] = *reinterpret_cast<const short8*>(
                            &LB[pc][wc >> 1][lb*64 + (((kk*4 + lq) ^ (lb & 7)) * 8)]);
                }
            }
            __builtin_amdgcn_s_setprio(1);
            #pragma unroll
            for (int kk = 0; kk < 2; ++kk)
                #pragma unroll
                for (int mi = 0; mi < 2; ++mi)
                    #pragma unroll
                    for (int n = 0; n < 4; ++n)
                        acc[q*2 + mi][n] = MFMA16(afr[mi][kk], bfr[n][kk], acc[q*2 + mi][n]);
            __builtin_amdgcn_s_setprio(0);
            if (q == 3 && kt + 1 < NT){
                if (kt + 2 < NT) asm volatile("s_waitcnt vmcnt(6)" ::: "memory");
                else             asm volatile("s_waitcnt vmcnt(0)" ::: "memory");
            }
            __builtin_amdgcn_s_barrier();
            asm volatile("" ::: "memory");
            __builtin_amdgcn_sched_barrier(0);
        }
    }

    #pragma unroll
    for (int a = 0; a < 8; ++a){
        int grow = m0 + wr*128 + (a >> 1)*32 + (a & 1)*16 + lq*4;
        #pragma unroll
        for (int n = 0; n < 4; ++n){
            int gcol = n0 + wc*64 + n*16 + l16;
            #pragma unroll
            for (int r = 0; r < 4; ++r)
                C[(size_t)(grow + r) * N + gcol] = f2b(acc[a][n][r]);
        }
    }
}

// ---------------- K2: qkv postprocess (rmsnorm + rope + concat + cat-rmsnorm) ----------------
__global__ __launch_bounds__(256) void qkv_post(
    const unsigned short* __restrict__ comb_lc, const unsigned short* __restrict__ comb_gc,
    const float* __restrict__ freqs,
    const float* __restrict__ q_lc_nw, const float* __restrict__ k_lc_nw,
    const float* __restrict__ q_gc_nw, const float* __restrict__ k_gc_nw,
    const float* __restrict__ q_cat_nw, const float* __restrict__ k_cat_nw,
    unsigned short* __restrict__ xq, unsigned short* __restrict__ xk,
    unsigned short* __restrict__ xv)
{
    __shared__ float qcat[16][128];
    __shared__ float kcat[16][128];
    __shared__ float rbuf[4][4];
    const int tok = blockIdx.x;
    const int s = tok & (SS - 1);
    const unsigned short* clc = comb_lc + (size_t)tok * TOT;
    const unsigned short* cgc = comb_gc + (size_t)tok * TOT;
    const int t = threadIdx.x;
    const int lane = t & 63, w = t >> 6;

    const unsigned short* segs[4] = { clc, clc + QD, cgc, cgc + QD };
    const float* wts[4] = { q_lc_nw, k_lc_nw, q_gc_nw, k_gc_nw };

    float ss4[4];
    #pragma unroll
    for (int sg = 0; sg < 4; ++sg){
        u16x4 v = *reinterpret_cast<const u16x4*>(segs[sg] + t * 4);
        float acc = 0.f;
        #pragma unroll
        for (int j = 0; j < 4; ++j){ float f = b2f(v[j]); acc += f * f; }
        ss4[sg] = acc;
    }
    #pragma unroll
    for (int sg = 0; sg < 4; ++sg){
        float v = ss4[sg];
        #pragma unroll
        for (int o = 32; o >= 1; o >>= 1) v += __shfl_xor(v, o);
        if (lane == 0) rbuf[sg][w] = v;
    }
    __syncthreads();
    float rms[4];
    #pragma unroll
    for (int sg = 0; sg < 4; ++sg){
        float tot = rbuf[sg][0] + rbuf[sg][1] + rbuf[sg][2] + rbuf[sg][3];
        rms[sg] = rsqrtf(tot * (1.f / QD) + EPS);
    }

    #pragma unroll
    for (int sg = 0; sg < 4; ++sg){
        const unsigned short* seg = segs[sg];
        const float* wt = wts[sg];
        const float rf = rms[sg];
        float (*dst)[128] = (sg == 0 || sg == 2) ? qcat : kcat;
        const int coff = (sg >= 2) ? 64 : 0;
        #pragma unroll
        for (int pi = 0; pi < 2; ++pi){
            int p = t + pi * 256;
            int h = p >> 5, j = p & 31;
            int idx = h * 64 + 2 * j;
            float xr = b2f(seg[idx])     * rf * wt[idx];
            float xi = b2f(seg[idx + 1]) * rf * wt[idx + 1];
            float fr = freqs[(size_t)s * 32 + j];
            float cs = __cosf(fr), sn = __sinf(fr);
            dst[h][coff + 2*j]     = xr * cs - xi * sn;
            dst[h][coff + 2*j + 1] = xr * sn + xi * cs;
        }
    }

    {
        int i0 = t * 4;
        int h = i0 >> 6, d = i0 & 63;
        u16x4 vlc = *reinterpret_cast<const u16x4*>(clc + 2048 + i0);
        u16x4 vgc = *reinterpret_cast<const u16x4*>(cgc + 2048 + i0);
        *reinterpret_cast<u16x4*>(&xv[(size_t)tok * DIM + h * 128 + d])      = vlc;
        *reinterpret_cast<u16x4*>(&xv[(size_t)tok * DIM + h * 128 + 64 + d]) = vgc;
    }
    __syncthreads();

    {
        int h = t >> 4, sub = t & 15;
        float sq = 0.f, sk = 0.f;
        #pragma unroll
        for (int j = 0; j < 8; ++j){
            float a = qcat[h][sub*8 + j]; sq += a * a;
            float b = kcat[h][sub*8 + j]; sk += b * b;
        }
        #pragma unroll
        for (int o = 1; o < 16; o <<= 1){ sq += __shfl_xor(sq, o); sk += __shfl_xor(sk, o); }
        float rq = rsqrtf(sq * (1.f / 128) + EPS);
        float rk = rsqrtf(sk * (1.f / 128) + EPS);
        u16x8 oq, ok;
        #pragma unroll
        for (int j = 0; j < 8; ++j){
            int d = sub*8 + j;
            oq[j] = f2b(qcat[h][d] * rq * q_cat_nw[d]);
            ok[j] = f2b(kcat[h][d] * rk * k_cat_nw[d]);
        }
        *reinterpret_cast<u16x8*>(&xq[(size_t)tok * DIM + h * 128 + sub*8]) = oq;
        *reinterpret_cast<u16x8*>(&xk[(size_t)tok * DIM + h * 128 + sub*8]) = ok;
    }
}

// ---------------- K4: V transpose -> xvT[b,h,d,s] ----------------
__global__ __launch_bounds__(256) void transpose_v(const unsigned short* __restrict__ xv,
                                                   unsigned short* __restrict__ xvT){
    __shared__ unsigned short tile[128][129];
    const int blk = blockIdx.x;
    const int st = blk & 15;
    const int bh = blk >> 4;
    const int b = bh >> 4, h = bh & 15;
    const int t = threadIdx.x;
    const int s0 = st * 128;
    #pragma unroll
    for (int i = 0; i < 8; ++i){
        int c = t + 256 * i;
        int r = c >> 4, dc = c & 15;
        u16x8 v = *reinterpret_cast<const u16x8*>(&xv[((size_t)(b*SS + s0 + r)) * DIM + h*HD + dc*8]);
        #pragma unroll
        for (int j = 0; j < 8; ++j) tile[r][dc*8 + j] = v[j];
    }
    __syncthreads();
    #pragma unroll
    for (int i = 0; i < 8; ++i){
        int c = t + 256 * i;
        int d = c >> 4, sc = c & 15;
        u16x8 o;
        #pragma unroll
        for (int j = 0; j < 8; ++j) o[j] = tile[sc*8 + j][d];
        *reinterpret_cast<u16x8*>(&xvT[((size_t)bh * HD + d) * SS + s0 + sc*8]) = o;
    }
}

// ---------------- K3: flash attention — QBLK=128, static-bias softmax (proven) -------------
__global__ __launch_bounds__(256) void attn_fwd(const unsigned short* __restrict__ xq,
                                                const unsigned short* __restrict__ xk,
                                                const unsigned short* __restrict__ xvT,
                                                unsigned short* __restrict__ attn_out){
    __shared__ __attribute__((aligned(16))) unsigned short Kl[2][64 * 128];
    __shared__ __attribute__((aligned(16))) unsigned short Vt[2][128 * 64];
    __shared__ __attribute__((aligned(16))) unsigned short Pl[4][2][16 * 64];
    const int blk = ((int)blockIdx.x & 7) * 64 + ((int)blockIdx.x >> 3);
    const int qt = blk & 15, h = (blk >> 4) & 15, b = blk >> 8;
    const int t = threadIdx.x, lane = t & 63, w = t >> 6;
    const int l16 = lane & 15, lq = lane >> 4;
    const float scale2 = 0.12751744751f;
    const float MBIAS = 16.6f;
    const int qbase = qt * 128 + w * 32;

    short8 qf[2][4];
    #pragma unroll
    for (int g = 0; g < 2; ++g)
        #pragma unroll
        for (int ks = 0; ks < 4; ++ks)
            qf[g][ks] = *reinterpret_cast<const short8*>(
                &xq[((size_t)(b*SS + qbase + g*16 + l16)) * DIM + h*HD + ks*32 + lq*8]);

    float psum[2] = {0.f, 0.f};
    f32x4 O[2][8];
    const f32x4 z = {0.f, 0.f, 0.f, 0.f};
    #pragma unroll
    for (int g = 0; g < 2; ++g)
        #pragma unroll
        for (int dn = 0; dn < 8; ++dn) O[g][dn] = z;

    const size_t kbase = (size_t)(b*SS) * DIM + h*HD;
    const size_t vbase = ((size_t)(b*NH + h)) * HD * SS;

    auto stage = [&](int kt, int bi){
        #pragma unroll
        for (int i = 0; i < 4; ++i){
            int slot = i*256 + w*64 + lane;
            int r = slot >> 4, dc = slot & 15;
            GLOAD16(&xk[kbase + (size_t)(kt*64 + r) * DIM + ((dc ^ (r & 7)) * 8)],
                    (char*)&Kl[bi][0] + (size_t)(i*256 + w*64) * 16);
            int d = slot >> 3, kc = slot & 7;
            GLOAD16(&xvT[vbase + (size_t)d * SS + kt*64 + ((kc ^ (d & 7)) * 8)],
                    (char*)&Vt[bi][0] + (size_t)(i*256 + w*64) * 16);
        }
    };

    stage(0, 0);
    __syncthreads();

    int cur = 0;

    for (int kt = 0; kt < SS/64; ++kt){
        if (kt + 1 < SS/64) stage(kt + 1, cur ^ 1);

        const unsigned short* Kc = Kl[cur];
        const unsigned short* Vc = Vt[cur];

        #pragma unroll
        for (int g = 0; g < 2; ++g){
            f32x4 St[4];
            #pragma unroll
            for (int kn = 0; kn < 4; ++kn) St[kn] = z;
            __builtin_amdgcn_s_setprio(1);
            #pragma unroll
            for (int kn = 0; kn < 4; ++kn){
                int kr = kn*16 + l16;
                #pragma unroll
                for (int ks = 0; ks < 4; ++ks){
                    short8 ak = *reinterpret_cast<const short8*>(
                        &Kc[kr*128 + (((ks*4 + lq) ^ (kr & 7)) * 8)]);
                    St[kn] = MFMA16(ak, qf[g][ks], St[kn]);
                }
            }
            __builtin_amdgcn_s_setprio(0);

            unsigned short* P = Pl[w][g];
            #pragma unroll
            for (int kn = 0; kn < 4; ++kn){
                float p0 = exp2_fast(St[kn][0]*scale2 - MBIAS);
                float p1 = exp2_fast(St[kn][1]*scale2 - MBIAS);
                float p2 = exp2_fast(St[kn][2]*scale2 - MBIAS);
                float p3 = exp2_fast(St[kn][3]*scale2 - MBIAS);
                psum[g] += (p0 + p1) + (p2 + p3);
                unsigned lo, hi;
                asm("v_cvt_pk_bf16_f32 %0, %1, %2" : "=v"(lo) : "v"(p0), "v"(p1));
                asm("v_cvt_pk_bf16_f32 %0, %1, %2" : "=v"(hi) : "v"(p2), "v"(p3));
                uint2 pk2; pk2.x = lo; pk2.y = hi;
                int kk = kn >> 1;
                int lqp = (kn & 1)*2 + (lq >> 1);
                *reinterpret_cast<uint2*>(&P[(kk*64 + lqp*16 + l16)*8 + (lq & 1)*4]) = pk2;
            }
        }
        asm volatile("s_waitcnt lgkmcnt(0)" ::: "memory");
        __builtin_amdgcn_sched_barrier(0);

        __builtin_amdgcn_s_setprio(1);
        #pragma unroll
        for (int kk = 0; kk < 2; ++kk){
            short8 pb0 = *reinterpret_cast<const short8*>(&Pl[w][0][(kk*64 + lq*16 + l16)*8]);
            short8 pb1 = *reinterpret_cast<const short8*>(&Pl[w][1][(kk*64 + lq*16 + l16)*8]);
            #pragma unroll
            for (int dn = 0; dn < 8; ++dn){
                int dr = dn*16 + l16;
                short8 av = *reinterpret_cast<const short8*>(
                    &Vc[dr*64 + (((kk*4 + lq) ^ (dr & 7)) * 8)]);
                O[0][dn] = MFMA16(av, pb0, O[0][dn]);
                O[1][dn] = MFMA16(av, pb1, O[1][dn]);
            }
        }
        __builtin_amdgcn_s_setprio(0);

        __syncthreads();
        cur ^= 1;
    }

    #pragma unroll
    for (int g = 0; g < 2; ++g){
        float ps = psum[g];
        ps += __shfl_xor(ps, 16);
        ps += __shfl_xor(ps, 32);
        float inv = 1.f / ps;
        #pragma unroll
        for (int dn = 0; dn < 8; ++dn){
            u16x4 o4;
            #pragma unroll
            for (int r = 0; r < 4; ++r) o4[r] = f2b(O[g][dn][r] * inv);
            *reinterpret_cast<u16x4*>(
                &attn_out[((size_t)(b*SS + qbase + g*16 + l16)) * DIM + h*HD + dn*16 + lq*4]) = o4;
        }
    }
}

// ---------------- K5: bias + rmsnorm epilogue, merged proj [NTOK][2*DIM] ----------------
__global__ __launch_bounds__(256) void proj_norm2(const unsigned short* __restrict__ proj,
                                                  const float* __restrict__ b_lo,
                                                  const float* __restrict__ b_go,
                                                  const float* __restrict__ w_lc,
                                                  const float* __restrict__ w_gc,
                                                  float* __restrict__ out){
    __shared__ float buf[DIM];
    __shared__ float rbuf[4];
    const int half = blockIdx.x >> 12;
    const int row  = blockIdx.x & (NTOK - 1);
    const unsigned short* p = proj + (size_t)row * (2*DIM) + (size_t)half * DIM;
    const float* bias = half ? b_go : b_lo;
    const float* w    = half ? w_gc : w_lc;
    float* o = out + (size_t)half * NTOK * DIM + (size_t)row * DIM;
    const int t = threadIdx.x;
    const int lane = t & 63, wv = t >> 6;
    float ssq = 0.f;
    #pragma unroll
    for (int i = 0; i < 8; ++i){
        int c = t + i * 256;
        float v = b2f(p[c]) + bias[c];
        buf[c] = v;
        ssq += v * v;
    }
    #pragma unroll
    for (int o2 = 32; o2 >= 1; o2 >>= 1) ssq += __shfl_xor(ssq, o2);
    if (lane == 0) rbuf[wv] = ssq;
    __syncthreads();
    float tot = rbuf[0] + rbuf[1] + rbuf[2] + rbuf[3];
    float rr = rsqrtf(tot * (1.f / DIM) + EPS);
    #pragma unroll
    for (int i = 0; i < 8; ++i){
        int c = t + i * 256;
        o[c] = buf[c] * rr * w[c];
    }
}

extern "C" void kernel_launch(void* const* d_in, const int* in_sizes, int n_in,
                              void* d_out, int out_size, void* d_ws, size_t ws_size,
                              hipStream_t stream)
{
    const float* local_c  = (const float*)d_in[0];
    const float* global_c = (const float*)d_in[1];
    const float* freqs    = (const float*)d_in[2];
    const float* W_lc     = (const float*)d_in[3];
    const float* W_gc     = (const float*)d_in[4];
    const float* q_lc_nw  = (const float*)d_in[5];
    const float* k_lc_nw  = (const float*)d_in[6];
    const float* q_gc_nw  = (const float*)d_in[7];
    const float* k_gc_nw  = (const float*)d_in[8];
    const float* q_cat_nw = (const float*)d_in[9];
    const float* k_cat_nw = (const float*)d_in[10];
    const float* W_lo     = (const float*)d_in[11];
    const float* b_lo     = (const float*)d_in[12];
    const float* lc_on_w  = (const float*)d_in[13];
    const float* W_go     = (const float*)d_in[14];
    const float* b_go     = (const float*)d_in[15];
    const float* gc_on_w  = (const float*)d_in[16];
    float* out = (float*)d_out;

    // ---- aliased workspace arena ----
    char* ws = (char*)d_ws;
    const size_t SZ_WLO  = (size_t)DIM * DIM * 2;
    const size_t SZ_WLC  = (size_t)TOT * DIM * 2;
    const size_t SZ_TOK2 = (size_t)NTOK * DIM * 2;
    const size_t SZ_COMB = (size_t)NTOK * TOT * 2;

    unsigned short* Wlo_b  = (unsigned short*)(ws);               // Wlo+Wgo contiguous => merged B
    unsigned short* Wgo_b  = (unsigned short*)(ws + SZ_WLO);
    char*           slotW  = ws + 2*SZ_WLO;
    unsigned short* Wlc_b  = (unsigned short*)(slotW);
    unsigned short* Wgc_b  = (unsigned short*)(slotW + SZ_WLC);
    unsigned short* xv     = (unsigned short*)(slotW);            // alias: Wlc/Wgc dead after QKV GEMM
    char*           slotE  = ws + 2*SZ_WLO + 2*SZ_WLC;
    char*           slotF  = slotE + SZ_TOK2;
    unsigned short* xq     = (unsigned short*)slotE;
    unsigned short* xk     = (unsigned short*)slotF;
    unsigned short* proj   = (unsigned short*)slotE;              // merged [NTOK][2*DIM]
    char*           slotG  = slotF + SZ_TOK2;
    char*           slotH  = slotG + SZ_COMB;
    unsigned short* comb_lc= (unsigned short*)slotG;
    unsigned short* comb_gc= (unsigned short*)slotH;
    unsigned short* xvT    = (unsigned short*)slotG;
    unsigned short* attn_o = (unsigned short*)slotH;
    (void)ws_size;

    // 1) weight converts only
    cvt_w4<<<2048, 256, 0, stream>>>(W_lc, W_gc, W_lo, W_go,
                                     Wlc_b, Wgc_b, Wlo_b, Wgo_b);

    // 2) both QKV GEMMs: 128^2, f32-A via T14 load-early/write-late, z-batched
    dim3 g1(TOT / 128, NTOK / 128, 2);
    gemm_qkv<<<g1, 256, 0, stream>>>(local_c, Wlc_b, comb_lc,
                                     global_c, Wgc_b, comb_gc, NTOK, TOT, DIM);

    // 3) norms + rope + concat
    qkv_post<<<NTOK, 256, 0, stream>>>(comb_lc, comb_gc, freqs,
                                       q_lc_nw, k_lc_nw, q_gc_nw, k_gc_nw,
                                       q_cat_nw, k_cat_nw, xq, xk, xv);

    // 4) V transpose
    transpose_v<<<512, 256, 0, stream>>>(xv, xvT);

    // 5) attention (QBLK=128)
    attn_fwd<<<512, 256, 0, stream>>>(xq, xk, xvT, attn_o);

    // 6) output projection: 256^2 8-phase (256 blocks = exactly 1/CU, no tail)
    dim3 g2(2 * DIM / 256, NTOK / 256, 1);
    gemm256<<<g2, 512, 0, stream>>>(attn_o, Wlo_b, proj,
                                    attn_o, Wlo_b, proj, NTOK, 2*DIM, DIM);

    // 7) final norms
    proj_norm2<<<2*NTOK, 256, 0, stream>>>(proj, b_lo, b_go, lc_on_w, gc_on_w, out);
}

// Round 18
// 358.123 us; speedup vs baseline: 1.1051x; 1.1032x over previous
//
#include <hip/hip_runtime.h>
#include <hip/hip_bf16.h>

#define DIM 2048
#define NH 16
#define HD 128
#define QD 1024
#define TOT 3072
#define BB 2
#define SS 2048
#define NTOK (BB*SS)
#define EPS 1e-5f

typedef __attribute__((ext_vector_type(4))) float f32x4;
typedef __attribute__((ext_vector_type(8))) short short8;
typedef __attribute__((ext_vector_type(8))) unsigned short u16x8;
typedef __attribute__((ext_vector_type(4))) unsigned short u16x4;

__device__ __forceinline__ float b2f(unsigned short u){
    unsigned int x = ((unsigned int)u) << 16;
    return __builtin_bit_cast(float, x);
}
__device__ __forceinline__ unsigned short f2b(float f){
    unsigned int x = __builtin_bit_cast(unsigned int, f);
    x = (x + 0x7fffu + ((x >> 16) & 1u)) >> 16;
    return (unsigned short)x;
}
__device__ __forceinline__ float exp2_fast(float x){
    float r;
    asm("v_exp_f32 %0, %1" : "=v"(r) : "v"(x));
    return r;
}
__device__ __forceinline__ void store_c(float* p, float v){ *p = v; }
__device__ __forceinline__ void store_c(unsigned short* p, float v){ *p = f2b(v); }

#define MFMA16(a,b,c) __builtin_amdgcn_mfma_f32_16x16x32_bf16((a),(b),(c),0,0,0)

#define GLOAD16(g, l) __builtin_amdgcn_global_load_lds( \
    (const __attribute__((address_space(1))) unsigned int*)(g), \
    (__attribute__((address_space(3))) unsigned int*)(l), 16, 0, 0)

// ---------------- K0: all six f32 -> bf16 converts in ONE launch ----------------
__device__ __forceinline__ void cvt8(const float* __restrict__ s,
                                     unsigned short* __restrict__ d, int i){
    const float4* p = reinterpret_cast<const float4*>(s + (size_t)i * 8);
    float4 a = p[0], b = p[1];
    u16x8 o;
    o[0]=f2b(a.x); o[1]=f2b(a.y); o[2]=f2b(a.z); o[3]=f2b(a.w);
    o[4]=f2b(b.x); o[5]=f2b(b.y); o[6]=f2b(b.z); o[7]=f2b(b.w);
    *reinterpret_cast<u16x8*>(d + (size_t)i * 8) = o;
}

__global__ __launch_bounds__(256) void cvt_multi(
    const float* __restrict__ s0, const float* __restrict__ s1,
    const float* __restrict__ s2, const float* __restrict__ s3,
    const float* __restrict__ s4, const float* __restrict__ s5,
    unsigned short* __restrict__ d0, unsigned short* __restrict__ d1,
    unsigned short* __restrict__ d2, unsigned short* __restrict__ d3,
    unsigned short* __restrict__ d4, unsigned short* __restrict__ d5)
{
    const int N0 = NTOK*DIM/8;
    const int N1 = N0 + NTOK*DIM/8;
    const int N2 = N1 + TOT*DIM/8;
    const int N3 = N2 + TOT*DIM/8;
    const int N4 = N3 + DIM*DIM/8;
    const int N5 = N4 + DIM*DIM/8;
    for (int i = blockIdx.x * blockDim.x + threadIdx.x; i < N5;
         i += gridDim.x * blockDim.x){
        if      (i < N0) cvt8(s0, d0, i);
        else if (i < N1) cvt8(s1, d1, i - N0);
        else if (i < N2) cvt8(s2, d2, i - N1);
        else if (i < N3) cvt8(s3, d3, i - N2);
        else if (i < N4) cvt8(s4, d4, i - N3);
        else             cvt8(s5, d5, i - N4);
    }
}

// ---------------- K1a: 128x128 NT GEMM — prefetch dbuf + T2 XOR swizzle (proven 122us) -----
// z-slice from HW dispatch id: XCDs 0-3 slice0, 4-7 slice1.
template<typename OutT>
__global__ __launch_bounds__(256) void gemm_nt(const unsigned short* __restrict__ A0,
                                               const unsigned short* __restrict__ B0,
                                               OutT* __restrict__ C0,
                                               const unsigned short* __restrict__ A1,
                                               const unsigned short* __restrict__ B1,
                                               OutT* __restrict__ C1,
                                               int M, int N, int K){
    __shared__ __attribute__((aligned(16))) unsigned short As[2][128*64];
    __shared__ __attribute__((aligned(16))) unsigned short Bs[2][128*64];
    const int t = threadIdx.x;
    const int lane = t & 63;
    const int w = t >> 6;
    const int wr = w >> 1, wc = w & 1;
    const int gx = gridDim.x;
    const int nwg = gx * gridDim.y;
    int zsel, swz;
    if (gridDim.z == 2){
        const int glin = (int)(blockIdx.z * nwg + blockIdx.y * gx + blockIdx.x);
        const int xcd = glin & 7;
        const int i = glin >> 3;
        zsel = xcd >> 2;
        swz = (xcd & 3) * (nwg >> 2) + i;
    } else {
        const int lin = (int)(blockIdx.y * gx + blockIdx.x);
        const int cpx = nwg >> 3;
        swz = (lin & 7) * cpx + (lin >> 3);
        zsel = 0;
    }
    const unsigned short* A = zsel ? A1 : A0;
    const unsigned short* B = zsel ? B1 : B0;
    OutT* C = zsel ? C1 : C0;
    const int m0 = (swz / gx) * 128, n0 = (swz % gx) * 128;
    const int l16 = lane & 15, lq = lane >> 4;

    f32x4 acc[4][4];
    const f32x4 z = {0.f, 0.f, 0.f, 0.f};
    #pragma unroll
    for (int m = 0; m < 4; ++m)
        #pragma unroll
        for (int n = 0; n < 4; ++n) acc[m][n] = z;

    auto stage = [&](int kt, int bi){
        #pragma unroll
        for (int i = 0; i < 4; ++i){
            int c = t + 256 * i;
            int row = c >> 3, c8 = c & 7;
            int cg = (c8 ^ (row & 7)) * 8;
            GLOAD16(&A[(size_t)(m0 + row) * K + kt + cg],
                    (char*)&As[bi][0] + (size_t)(i * 256 + w * 64) * 16);
            GLOAD16(&B[(size_t)(n0 + row) * K + kt + cg],
                    (char*)&Bs[bi][0] + (size_t)(i * 256 + w * 64) * 16);
        }
    };

    stage(0, 0);
    __syncthreads();
    int cur = 0;

    for (int kt = 0; kt < K; kt += 64){
        if (kt + 64 < K) stage(kt + 64, cur ^ 1);
        #pragma unroll
        for (int kk = 0; kk < 2; ++kk){
            short8 af[4], bf[4];
            #pragma unroll
            for (int m = 0; m < 4; ++m){
                int row = wr*64 + m*16 + l16;
                af[m] = *reinterpret_cast<const short8*>(
                    &As[cur][row*64 + (((kk*4 + lq) ^ (row & 7)) * 8)]);
            }
            #pragma unroll
            for (int n = 0; n < 4; ++n){
                int row = wc*64 + n*16 + l16;
                bf[n] = *reinterpret_cast<const short8*>(
                    &Bs[cur][row*64 + (((kk*4 + lq) ^ (row & 7)) * 8)]);
            }
            #pragma unroll
            for (int m = 0; m < 4; ++m)
                #pragma unroll
                for (int n = 0; n < 4; ++n)
                    acc[m][n] = MFMA16(af[m], bf[n], acc[m][n]);
        }
        __syncthreads();
        cur ^= 1;
    }
    #pragma unroll
    for (int m = 0; m < 4; ++m){
        int grow = m0 + wr*64 + m*16 + lq*4;
        #pragma unroll
        for (int n = 0; n < 4; ++n){
            int gcol = n0 + wc*64 + n*16 + l16;
            #pragma unroll
            for (int r = 0; r < 4; ++r)
                store_c(&C[(size_t)(grow + r) * N + gcol], acc[m][n][r]);
        }
    }
}

// ---------------- K1b: 256x256 8-phase GEMM — used for proj (256 blocks = 1/CU) ------------
__global__ __launch_bounds__(512, 2) void gemm256(
    const unsigned short* __restrict__ A0, const unsigned short* __restrict__ B0,
    unsigned short* __restrict__ C0,
    const unsigned short* __restrict__ A1, const unsigned short* __restrict__ B1,
    unsigned short* __restrict__ C1, int M, int N, int K)
{
    __shared__ __attribute__((aligned(16))) unsigned short LA[2][2][128*64];
    __shared__ __attribute__((aligned(16))) unsigned short LB[2][2][128*64];
    const int t = threadIdx.x;
    const int lane = t & 63, w = t >> 6;
    const int wr = w >> 2, wc = w & 3;
    const int l16 = lane & 15, lq = lane >> 4;
    const int gx = gridDim.x;
    const int nwg = gx * gridDim.y;
    int zsel, swz;
    if (gridDim.z == 2){
        const int glin = (int)(blockIdx.z * nwg + blockIdx.y * gx + blockIdx.x);
        const int xcd = glin & 7;
        const int i = glin >> 3;
        zsel = xcd >> 2;
        swz = (xcd & 3) * (nwg >> 2) + i;
    } else {
        const int lin = (int)(blockIdx.y * gx + blockIdx.x);
        swz = (lin & 7) * (nwg >> 3) + (lin >> 3);
        zsel = 0;
    }
    const unsigned short* A = zsel ? A1 : A0;
    const unsigned short* B = zsel ? B1 : B0;
    unsigned short* C = zsel ? C1 : C0;
    const int m0 = (swz / gx) * 256, n0 = (swz % gx) * 256;

    f32x4 acc[8][4];
    const f32x4 z = {0.f, 0.f, 0.f, 0.f};
    #pragma unroll
    for (int a = 0; a < 8; ++a)
        #pragma unroll
        for (int n = 0; n < 4; ++n) acc[a][n] = z;

    auto part = [&](const unsigned short* S, int rowbase, int kt, int j2, unsigned short* slab){
        int row = j2*64 + (t >> 3);
        int ch  = t & 7;
        GLOAD16(&S[(size_t)(rowbase + row) * K + kt*64 + ((ch ^ (row & 7)) * 8)],
                (char*)slab + (size_t)(j2*512 + w*64) * 16);
    };

    const int NT = K >> 6;
    part(B, n0+0,   0, 0, &LB[0][0][0]); part(B, n0+0,   0, 1, &LB[0][0][0]);
    part(B, n0+128, 0, 0, &LB[0][1][0]); part(B, n0+128, 0, 1, &LB[0][1][0]);
    part(A, m0+0,   0, 0, &LA[0][0][0]); part(A, m0+128, 0, 0, &LA[0][1][0]);
    part(A, m0+0,   0, 1, &LA[0][0][0]); part(A, m0+128, 0, 1, &LA[0][1][0]);
    if (NT > 1){
        part(B, n0+0,   1, 0, &LB[1][0][0]); part(B, n0+0,   1, 1, &LB[1][0][0]);
        part(A, m0+0,   1, 0, &LA[1][0][0]); part(A, m0+128, 1, 0, &LA[1][1][0]);
        part(B, n0+128, 1, 0, &LB[1][1][0]); part(B, n0+128, 1, 1, &LB[1][1][0]);
        asm volatile("s_waitcnt vmcnt(6)" ::: "memory");
    } else {
        asm volatile("s_waitcnt vmcnt(0)" ::: "memory");
    }
    __builtin_amdgcn_s_barrier();
    asm volatile("" ::: "memory");
    __builtin_amdgcn_sched_barrier(0);

    for (int kt = 0; kt < NT; ++kt){
        const int pc = kt & 1;
        const int p1 = pc ^ 1;
        short8 bfr[4][2];
        #pragma unroll
        for (int q = 0; q < 4; ++q){
            if (q == 0 && kt + 1 < NT){
                part(A, m0+0,   kt+1, 1, &LA[p1][0][0]);
                part(A, m0+128, kt+1, 1, &LA[p1][1][0]);
            }
            if (q == 1 && kt + 2 < NT){
                part(B, n0+0,   kt+2, 0, &LB[pc][0][0]);
                part(B, n0+0,   kt+2, 1, &LB[pc][0][0]);
            }
            if (q == 2 && kt + 2 < NT){
                part(A, m0+0,   kt+2, 0, &LA[pc][0][0]);
                part(A, m0+128, kt+2, 0, &LA[pc][1][0]);
            }
            if (q == 3 && kt + 2 < NT){
                part(B, n0+128, kt+2, 0, &LB[pc][1][0]);
                part(B, n0+128, kt+2, 1, &LB[pc][1][0]);
            }
            short8 afr[2][2];
            #pragma unroll
            for (int mi = 0; mi < 2; ++mi){
                int lr = q*32 + mi*16 + l16;
                #pragma unroll
                for (int kk = 0; kk < 2; ++kk)
                    afr[mi][kk] = *reinterpret_cast<const short8*>(
                        &LA[pc][wr][lr*64 + (((kk*4 + lq) ^ (lr & 7)) * 8)]);
            }
            if (q == 0){
                #pragma unroll
                for (int n = 0; n < 4; ++n){
                    int lb = (wc & 1)*64 + n*16 + l16;
                    #pragma unroll
                    for (int kk = 0; kk < 2; ++kk)
                        bfr[n][kk] = *reinterpret_cast<const short8*>(
                            &LB[pc][wc >> 1][lb*64 + (((kk*4 + lq) ^ (lb & 7)) * 8)]);
                }
            }
            __builtin_amdgcn_s_setprio(1);
            #pragma unroll
            for (int kk = 0; kk < 2; ++kk)
                #pragma unroll
                for (int mi = 0; mi < 2; ++mi)
                    #pragma unroll
                    for (int n = 0; n < 4; ++n)
                        acc[q*2 + mi][n] = MFMA16(afr[mi][kk], bfr[n][kk], acc[q*2 + mi][n]);
            __builtin_amdgcn_s_setprio(0);
            if (q == 3 && kt + 1 < NT){
                if (kt + 2 < NT) asm volatile("s_waitcnt vmcnt(6)" ::: "memory");
                else             asm volatile("s_waitcnt vmcnt(0)" ::: "memory");
            }
            __builtin_amdgcn_s_barrier();
            asm volatile("" ::: "memory");
            __builtin_amdgcn_sched_barrier(0);
        }
    }

    #pragma unroll
    for (int a = 0; a < 8; ++a){
        int grow = m0 + wr*128 + (a >> 1)*32 + (a & 1)*16 + lq*4;
        #pragma unroll
        for (int n = 0; n < 4; ++n){
            int gcol = n0 + wc*64 + n*16 + l16;
            #pragma unroll
            for (int r = 0; r < 4; ++r)
                C[(size_t)(grow + r) * N + gcol] = f2b(acc[a][n][r]);
        }
    }
}

// ---------------- K2: qkv postprocess (rmsnorm + rope + concat + cat-rmsnorm) ----------------
__global__ __launch_bounds__(256) void qkv_post(
    const unsigned short* __restrict__ comb_lc, const unsigned short* __restrict__ comb_gc,
    const float* __restrict__ freqs,
    const float* __restrict__ q_lc_nw, const float* __restrict__ k_lc_nw,
    const float* __restrict__ q_gc_nw, const float* __restrict__ k_gc_nw,
    const float* __restrict__ q_cat_nw, const float* __restrict__ k_cat_nw,
    unsigned short* __restrict__ xq, unsigned short* __restrict__ xk,
    unsigned short* __restrict__ xv)
{
    __shared__ float qcat[16][128];
    __shared__ float kcat[16][128];
    __shared__ float rbuf[4][4];
    const int tok = blockIdx.x;
    const int s = tok & (SS - 1);
    const unsigned short* clc = comb_lc + (size_t)tok * TOT;
    const unsigned short* cgc = comb_gc + (size_t)tok * TOT;
    const int t = threadIdx.x;
    const int lane = t & 63, w = t >> 6;

    const unsigned short* segs[4] = { clc, clc + QD, cgc, cgc + QD };
    const float* wts[4] = { q_lc_nw, k_lc_nw, q_gc_nw, k_gc_nw };

    float ss4[4];
    #pragma unroll
    for (int sg = 0; sg < 4; ++sg){
        u16x4 v = *reinterpret_cast<const u16x4*>(segs[sg] + t * 4);
        float acc = 0.f;
        #pragma unroll
        for (int j = 0; j < 4; ++j){ float f = b2f(v[j]); acc += f * f; }
        ss4[sg] = acc;
    }
    #pragma unroll
    for (int sg = 0; sg < 4; ++sg){
        float v = ss4[sg];
        #pragma unroll
        for (int o = 32; o >= 1; o >>= 1) v += __shfl_xor(v, o);
        if (lane == 0) rbuf[sg][w] = v;
    }
    __syncthreads();
    float rms[4];
    #pragma unroll
    for (int sg = 0; sg < 4; ++sg){
        float tot = rbuf[sg][0] + rbuf[sg][1] + rbuf[sg][2] + rbuf[sg][3];
        rms[sg] = rsqrtf(tot * (1.f / QD) + EPS);
    }

    #pragma unroll
    for (int sg = 0; sg < 4; ++sg){
        const unsigned short* seg = segs[sg];
        const float* wt = wts[sg];
        const float rf = rms[sg];
        float (*dst)[128] = (sg == 0 || sg == 2) ? qcat : kcat;
        const int coff = (sg >= 2) ? 64 : 0;
        #pragma unroll
        for (int pi = 0; pi < 2; ++pi){
            int p = t + pi * 256;
            int h = p >> 5, j = p & 31;
            int idx = h * 64 + 2 * j;
            float xr = b2f(seg[idx])     * rf * wt[idx];
            float xi = b2f(seg[idx + 1]) * rf * wt[idx + 1];
            float fr = freqs[(size_t)s * 32 + j];
            float cs = __cosf(fr), sn = __sinf(fr);
            dst[h][coff + 2*j]     = xr * cs - xi * sn;
            dst[h][coff + 2*j + 1] = xr * sn + xi * cs;
        }
    }

    {
        int i0 = t * 4;
        int h = i0 >> 6, d = i0 & 63;
        u16x4 vlc = *reinterpret_cast<const u16x4*>(clc + 2048 + i0);
        u16x4 vgc = *reinterpret_cast<const u16x4*>(cgc + 2048 + i0);
        *reinterpret_cast<u16x4*>(&xv[(size_t)tok * DIM + h * 128 + d])      = vlc;
        *reinterpret_cast<u16x4*>(&xv[(size_t)tok * DIM + h * 128 + 64 + d]) = vgc;
    }
    __syncthreads();

    {
        int h = t >> 4, sub = t & 15;
        float sq = 0.f, sk = 0.f;
        #pragma unroll
        for (int j = 0; j < 8; ++j){
            float a = qcat[h][sub*8 + j]; sq += a * a;
            float b = kcat[h][sub*8 + j]; sk += b * b;
        }
        #pragma unroll
        for (int o = 1; o < 16; o <<= 1){ sq += __shfl_xor(sq, o); sk += __shfl_xor(sk, o); }
        float rq = rsqrtf(sq * (1.f / 128) + EPS);
        float rk = rsqrtf(sk * (1.f / 128) + EPS);
        u16x8 oq, ok;
        #pragma unroll
        for (int j = 0; j < 8; ++j){
            int d = sub*8 + j;
            oq[j] = f2b(qcat[h][d] * rq * q_cat_nw[d]);
            ok[j] = f2b(kcat[h][d] * rk * k_cat_nw[d]);
        }
        *reinterpret_cast<u16x8*>(&xq[(size_t)tok * DIM + h * 128 + sub*8]) = oq;
        *reinterpret_cast<u16x8*>(&xk[(size_t)tok * DIM + h * 128 + sub*8]) = ok;
    }
}

// ---------------- K4: V transpose -> xvT[b,h,d,s] ----------------
__global__ __launch_bounds__(256) void transpose_v(const unsigned short* __restrict__ xv,
                                                   unsigned short* __restrict__ xvT){
    __shared__ unsigned short tile[128][129];
    const int blk = blockIdx.x;
    const int st = blk & 15;
    const int bh = blk >> 4;
    const int b = bh >> 4, h = bh & 15;
    const int t = threadIdx.x;
    const int s0 = st * 128;
    #pragma unroll
    for (int i = 0; i < 8; ++i){
        int c = t + 256 * i;
        int r = c >> 4, dc = c & 15;
        u16x8 v = *reinterpret_cast<const u16x8*>(&xv[((size_t)(b*SS + s0 + r)) * DIM + h*HD + dc*8]);
        #pragma unroll
        for (int j = 0; j < 8; ++j) tile[r][dc*8 + j] = v[j];
    }
    __syncthreads();
    #pragma unroll
    for (int i = 0; i < 8; ++i){
        int c = t + 256 * i;
        int d = c >> 4, sc = c & 15;
        u16x8 o;
        #pragma unroll
        for (int j = 0; j < 8; ++j) o[j] = tile[sc*8 + j][d];
        *reinterpret_cast<u16x8*>(&xvT[((size_t)bh * HD + d) * SS + s0 + sc*8]) = o;
    }
}

// ---------------- K3: flash attention — QBLK=128, static-bias softmax (proven) -------------
__global__ __launch_bounds__(256) void attn_fwd(const unsigned short* __restrict__ xq,
                                                const unsigned short* __restrict__ xk,
                                                const unsigned short* __restrict__ xvT,
                                                unsigned short* __restrict__ attn_out){
    __shared__ __attribute__((aligned(16))) unsigned short Kl[2][64 * 128];
    __shared__ __attribute__((aligned(16))) unsigned short Vt[2][128 * 64];
    __shared__ __attribute__((aligned(16))) unsigned short Pl[4][2][16 * 64];
    const int blk = ((int)blockIdx.x & 7) * 64 + ((int)blockIdx.x >> 3);
    const int qt = blk & 15, h = (blk >> 4) & 15, b = blk >> 8;
    const int t = threadIdx.x, lane = t & 63, w = t >> 6;
    const int l16 = lane & 15, lq = lane >> 4;
    const float scale2 = 0.12751744751f;
    const float MBIAS = 16.6f;
    const int qbase = qt * 128 + w * 32;

    short8 qf[2][4];
    #pragma unroll
    for (int g = 0; g < 2; ++g)
        #pragma unroll
        for (int ks = 0; ks < 4; ++ks)
            qf[g][ks] = *reinterpret_cast<const short8*>(
                &xq[((size_t)(b*SS + qbase + g*16 + l16)) * DIM + h*HD + ks*32 + lq*8]);

    float psum[2] = {0.f, 0.f};
    f32x4 O[2][8];
    const f32x4 z = {0.f, 0.f, 0.f, 0.f};
    #pragma unroll
    for (int g = 0; g < 2; ++g)
        #pragma unroll
        for (int dn = 0; dn < 8; ++dn) O[g][dn] = z;

    const size_t kbase = (size_t)(b*SS) * DIM + h*HD;
    const size_t vbase = ((size_t)(b*NH + h)) * HD * SS;

    auto stage = [&](int kt, int bi){
        #pragma unroll
        for (int i = 0; i < 4; ++i){
            int slot = i*256 + w*64 + lane;
            int r = slot >> 4, dc = slot & 15;
            GLOAD16(&xk[kbase + (size_t)(kt*64 + r) * DIM + ((dc ^ (r & 7)) * 8)],
                    (char*)&Kl[bi][0] + (size_t)(i*256 + w*64) * 16);
            int d = slot >> 3, kc = slot & 7;
            GLOAD16(&xvT[vbase + (size_t)d * SS + kt*64 + ((kc ^ (d & 7)) * 8)],
                    (char*)&Vt[bi][0] + (size_t)(i*256 + w*64) * 16);
        }
    };

    stage(0, 0);
    __syncthreads();

    int cur = 0;

    for (int kt = 0; kt < SS/64; ++kt){
        if (kt + 1 < SS/64) stage(kt + 1, cur ^ 1);

        const unsigned short* Kc = Kl[cur];
        const unsigned short* Vc = Vt[cur];

        #pragma unroll
        for (int g = 0; g < 2; ++g){
            f32x4 St[4];
            #pragma unroll
            for (int kn = 0; kn < 4; ++kn) St[kn] = z;
            __builtin_amdgcn_s_setprio(1);
            #pragma unroll
            for (int kn = 0; kn < 4; ++kn){
                int kr = kn*16 + l16;
                #pragma unroll
                for (int ks = 0; ks < 4; ++ks){
                    short8 ak = *reinterpret_cast<const short8*>(
                        &Kc[kr*128 + (((ks*4 + lq) ^ (kr & 7)) * 8)]);
                    St[kn] = MFMA16(ak, qf[g][ks], St[kn]);
                }
            }
            __builtin_amdgcn_s_setprio(0);

            unsigned short* P = Pl[w][g];
            #pragma unroll
            for (int kn = 0; kn < 4; ++kn){
                float p0 = exp2_fast(St[kn][0]*scale2 - MBIAS);
                float p1 = exp2_fast(St[kn][1]*scale2 - MBIAS);
                float p2 = exp2_fast(St[kn][2]*scale2 - MBIAS);
                float p3 = exp2_fast(St[kn][3]*scale2 - MBIAS);
                psum[g] += (p0 + p1) + (p2 + p3);
                unsigned lo, hi;
                asm("v_cvt_pk_bf16_f32 %0, %1, %2" : "=v"(lo) : "v"(p0), "v"(p1));
                asm("v_cvt_pk_bf16_f32 %0, %1, %2" : "=v"(hi) : "v"(p2), "v"(p3));
                uint2 pk2; pk2.x = lo; pk2.y = hi;
                int kk = kn >> 1;
                int lqp = (kn & 1)*2 + (lq >> 1);
                *reinterpret_cast<uint2*>(&P[(kk*64 + lqp*16 + l16)*8 + (lq & 1)*4]) = pk2;
            }
        }
        asm volatile("s_waitcnt lgkmcnt(0)" ::: "memory");
        __builtin_amdgcn_sched_barrier(0);

        __builtin_amdgcn_s_setprio(1);
        #pragma unroll
        for (int kk = 0; kk < 2; ++kk){
            short8 pb0 = *reinterpret_cast<const short8*>(&Pl[w][0][(kk*64 + lq*16 + l16)*8]);
            short8 pb1 = *reinterpret_cast<const short8*>(&Pl[w][1][(kk*64 + lq*16 + l16)*8]);
            #pragma unroll
            for (int dn = 0; dn < 8; ++dn){
                int dr = dn*16 + l16;
                short8 av = *reinterpret_cast<const short8*>(
                    &Vc[dr*64 + (((kk*4 + lq) ^ (dr & 7)) * 8)]);
                O[0][dn] = MFMA16(av, pb0, O[0][dn]);
                O[1][dn] = MFMA16(av, pb1, O[1][dn]);
            }
        }
        __builtin_amdgcn_s_setprio(0);

        __syncthreads();
        cur ^= 1;
    }

    #pragma unroll
    for (int g = 0; g < 2; ++g){
        float ps = psum[g];
        ps += __shfl_xor(ps, 16);
        ps += __shfl_xor(ps, 32);
        float inv = 1.f / ps;
        #pragma unroll
        for (int dn = 0; dn < 8; ++dn){
            u16x4 o4;
            #pragma unroll
            for (int r = 0; r < 4; ++r) o4[r] = f2b(O[g][dn][r] * inv);
            *reinterpret_cast<u16x4*>(
                &attn_out[((size_t)(b*SS + qbase + g*16 + l16)) * DIM + h*HD + dn*16 + lq*4]) = o4;
        }
    }
}

// ---------------- K5: bias + rmsnorm epilogue, merged proj [NTOK][2*DIM] ----------------
__global__ __launch_bounds__(256) void proj_norm2(const unsigned short* __restrict__ proj,
                                                  const float* __restrict__ b_lo,
                                                  const float* __restrict__ b_go,
                                                  const float* __restrict__ w_lc,
                                                  const float* __restrict__ w_gc,
                                                  float* __restrict__ out){
    __shared__ float buf[DIM];
    __shared__ float rbuf[4];
    const int half = blockIdx.x >> 12;
    const int row  = blockIdx.x & (NTOK - 1);
    const unsigned short* p = proj + (size_t)row * (2*DIM) + (size_t)half * DIM;
    const float* bias = half ? b_go : b_lo;
    const float* w    = half ? w_gc : w_lc;
    float* o = out + (size_t)half * NTOK * DIM + (size_t)row * DIM;
    const int t = threadIdx.x;
    const int lane = t & 63, wv = t >> 6;
    float ssq = 0.f;
    #pragma unroll
    for (int i = 0; i < 8; ++i){
        int c = t + i * 256;
        float v = b2f(p[c]) + bias[c];
        buf[c] = v;
        ssq += v * v;
    }
    #pragma unroll
    for (int o2 = 32; o2 >= 1; o2 >>= 1) ssq += __shfl_xor(ssq, o2);
    if (lane == 0) rbuf[wv] = ssq;
    __syncthreads();
    float tot = rbuf[0] + rbuf[1] + rbuf[2] + rbuf[3];
    float rr = rsqrtf(tot * (1.f / DIM) + EPS);
    #pragma unroll
    for (int i = 0; i < 8; ++i){
        int c = t + i * 256;
        o[c] = buf[c] * rr * w[c];
    }
}

extern "C" void kernel_launch(void* const* d_in, const int* in_sizes, int n_in,
                              void* d_out, int out_size, void* d_ws, size_t ws_size,
                              hipStream_t stream)
{
    const float* local_c  = (const float*)d_in[0];
    const float* global_c = (const float*)d_in[1];
    const float* freqs    = (const float*)d_in[2];
    const float* W_lc     = (const float*)d_in[3];
    const float* W_gc     = (const float*)d_in[4];
    const float* q_lc_nw  = (const float*)d_in[5];
    const float* k_lc_nw  = (const float*)d_in[6];
    const float* q_gc_nw  = (const float*)d_in[7];
    const float* k_gc_nw  = (const float*)d_in[8];
    const float* q_cat_nw = (const float*)d_in[9];
    const float* k_cat_nw = (const float*)d_in[10];
    const float* W_lo     = (const float*)d_in[11];
    const float* b_lo     = (const float*)d_in[12];
    const float* lc_on_w  = (const float*)d_in[13];
    const float* W_go     = (const float*)d_in[14];
    const float* b_go     = (const float*)d_in[15];
    const float* gc_on_w  = (const float*)d_in[16];
    float* out = (float*)d_out;

    // ---- aliased workspace arena ----
    char* ws = (char*)d_ws;
    const size_t SZ_WLO  = (size_t)DIM * DIM * 2;
    const size_t SZ_WLC  = (size_t)TOT * DIM * 2;
    const size_t SZ_TOK2 = (size_t)NTOK * DIM * 2;
    const size_t SZ_COMB = (size_t)NTOK * TOT * 2;

    unsigned short* Wlo_b  = (unsigned short*)(ws);               // Wlo+Wgo contiguous => merged B
    unsigned short* Wgo_b  = (unsigned short*)(ws + SZ_WLO);
    char*           slotW  = ws + 2*SZ_WLO;
    unsigned short* Wlc_b  = (unsigned short*)(slotW);
    unsigned short* Wgc_b  = (unsigned short*)(slotW + SZ_WLC);
    unsigned short* xv     = (unsigned short*)(slotW);            // alias: Wlc/Wgc dead after QKV GEMM
    char*           slotE  = ws + 2*SZ_WLO + 2*SZ_WLC;
    char*           slotF  = slotE + SZ_TOK2;
    unsigned short* xb_lc  = (unsigned short*)slotE;
    unsigned short* xb_gc  = (unsigned short*)slotF;
    unsigned short* xq     = (unsigned short*)slotE;
    unsigned short* xk     = (unsigned short*)slotF;
    unsigned short* proj   = (unsigned short*)slotE;              // merged [NTOK][2*DIM]
    char*           slotG  = slotF + SZ_TOK2;
    char*           slotH  = slotG + SZ_COMB;
    unsigned short* comb_lc= (unsigned short*)slotG;
    unsigned short* comb_gc= (unsigned short*)slotH;
    unsigned short* xvT    = (unsigned short*)slotG;
    unsigned short* attn_o = (unsigned short*)slotH;
    (void)ws_size;

    // 1) converts (all six tensors)
    cvt_multi<<<2048, 256, 0, stream>>>(local_c, global_c, W_lc, W_gc, W_lo, W_go,
                                        xb_lc, xb_gc, Wlc_b, Wgc_b, Wlo_b, Wgo_b);

    // 2) both QKV GEMMs: 128^2 tile, z-batched (1536 blocks -> no tail; proven 122 us)
    dim3 g1(TOT / 128, NTOK / 128, 2);
    gemm_nt<unsigned short><<<g1, 256, 0, stream>>>(xb_lc, Wlc_b, comb_lc,
                                                    xb_gc, Wgc_b, comb_gc, NTOK, TOT, DIM);

    // 3) norms + rope + concat
    qkv_post<<<NTOK, 256, 0, stream>>>(comb_lc, comb_gc, freqs,
                                       q_lc_nw, k_lc_nw, q_gc_nw, k_gc_nw,
                                       q_cat_nw, k_cat_nw, xq, xk, xv);

    // 4) V transpose
    transpose_v<<<512, 256, 0, stream>>>(xv, xvT);

    // 5) attention (QBLK=128)
    attn_fwd<<<512, 256, 0, stream>>>(xq, xk, xvT, attn_o);

    // 6) output projection: 256^2 8-phase (256 blocks = exactly 1/CU, no tail)
    dim3 g2(2 * DIM / 256, NTOK / 256, 1);
    gemm256<<<g2, 512, 0, stream>>>(attn_o, Wlo_b, proj,
                                    attn_o, Wlo_b, proj, NTOK, 2*DIM, DIM);

    // 7) final norms
    proj_norm2<<<2*NTOK, 256, 0, stream>>>(proj, b_lo, b_go, lc_on_w, gc_on_w, out);
}